// Round 4
// baseline (701.121 us; speedup 1.0000x reference)
//
#include <hip/hip_runtime.h>
#include <hip/hip_bf16.h>

#define NR   8192
#define CIN  200
#define CNN  128
#define NCH  32
#define JC   256
#define BN_EPS 1e-5f
#define NBLK 512

// ws float offsets
#define OFF_BNPART 64                        // 64 blocks * 400
#define OFF_DTH    (OFF_BNPART + 64 * 400)
#define OFF_V2     (OFF_DTH + NR * CNN)
#define OFF_PART   (OFF_V2 + NR * 8)

// grid barrier: all NBLK blocks co-resident (launch_bounds(256,2), LDS 48KB -> 2 blocks/CU)
#define GBAR() do {                                                              \
    __syncthreads();                                                             \
    if (t == 0) {                                                                \
        __threadfence();                                                         \
        ++ep;                                                                    \
        __hip_atomic_fetch_add(bar, 1u, __ATOMIC_RELEASE, __HIP_MEMORY_SCOPE_AGENT); \
        const unsigned tgt = (unsigned)ep * NBLK;                                \
        while (__hip_atomic_load(bar, __ATOMIC_ACQUIRE, __HIP_MEMORY_SCOPE_AGENT) < tgt) \
            __builtin_amdgcn_s_sleep(8);                                         \
        __threadfence();                                                         \
    }                                                                            \
    __syncthreads();                                                             \
} while (0)

__global__ __launch_bounds__(256, 2) void mega_k(
    const float* __restrict__ H,    const float* __restrict__ alpha_p,
    const float* __restrict__ gamma,const float* __restrict__ beta,
    const float* __restrict__ w1,   const float* __restrict__ b1,
    const float* __restrict__ wdt,  const float* __restrict__ bdt,
    const float* __restrict__ wdtd, const float* __restrict__ bdtd,
    const float* __restrict__ aw1,  const float* __restrict__ ab1,
    const float* __restrict__ aw2,  const float* __restrict__ ab2,
    const float* __restrict__ aw3,  const float* __restrict__ ab3,
    const float* __restrict__ aw4,  const float* __restrict__ ab4,
    float* __restrict__ ws, float* __restrict__ outV, float* __restrict__ outHR)
{
    __shared__ float4 smem4[3072];            // 48 KB
    float* smem = (float*)smem4;

    unsigned* bar = (unsigned*)ws;
    float* bnpart = ws + OFF_BNPART;
    float* DTH    = ws + OFF_DTH;
    float* V2     = ws + OFF_V2;
    float* part   = ws + OFF_PART;

    const int bid = blockIdx.x;
    const int t   = threadIdx.x;
    int ep = 0;

    // ---------------- P0: BN partial sums (64 blocks x 128 rows) ----------
    if (bid < 64 && t < CIN) {
        const float* p = H + (size_t)bid * 128 * CIN + t;
        float s = 0.f, q = 0.f;
        #pragma unroll 8
        for (int r = 0; r < 128; ++r) { float v = p[(size_t)r * CIN]; s += v; q += v * v; }
        bnpart[bid * 400 + t]       = s;
        bnpart[bid * 400 + 200 + t] = q;
    }
    GBAR();

    // ---------------- P2: BN finalize (per-block) + dual GEMM -------------
    {
        float* scs  = smem;          // 256
        float* shs  = smem + 256;    // 256
        float* bias = smem + 512;    // 128
        float* aw1s = smem + 768;    // 1280
        float* aw2s = smem + 2048;   // 50
        float* ab1s = smem + 2112;   // 10
        float* ab2s = smem + 2128;   // 5
        float* As   = smem + 2144;   // [8][36]
        float* Bs   = smem + 2432;   // [8][136]
        float* Ct   = smem + 3520;   // [32][133]
        float* v1s  = smem + 7776;   // [32][12]

        const bool isV = (bid < 256);
        const int  m0  = (bid & 255) * 32;

        if (t < CIN) {
            float s = 0.f, q = 0.f;
            const float* p = bnpart + t;
            #pragma unroll 8
            for (int b = 0; b < 64; ++b) { s += p[b * 400]; q += p[b * 400 + 200]; }
            float mu  = s * (1.f / NR);
            float var = q * (1.f / NR) - mu * mu;
            float sc  = rsqrtf(var + BN_EPS) * gamma[t];
            scs[t] = sc; shs[t] = beta[t] - mu * sc;
        }
        if (t < CNN) bias[t] = isV ? b1[t] : bdt[t];
        if (isV) {
            for (int i = t; i < 1280; i += 256) aw1s[i] = aw1[i];
            if (t < 50) aw2s[t] = aw2[t];
            if (t < 10) ab1s[t] = ab1[t];
            if (t < 5)  ab2s[t] = ab2[t];
        }
        const int am = t >> 3, ak = t & 7;
        const int bn_ = t >> 1, bk4 = (t & 1) * 4;
        const float* brow = (isV ? w1 : wdt) + (size_t)bn_ * CIN + bk4;
        const float* arow = H + (size_t)(m0 + am) * CIN + ak;
        const int tx = t & 31, ty = t >> 5;
        float acc[4][4] = {};
        __syncthreads();

        for (int k0 = 0; k0 < CIN; k0 += 8) {
            const int k = k0 + ak;
            float  aval = arow[k0] * scs[k] + shs[k];
            float4 bv   = *(const float4*)(brow + k0);
            __syncthreads();
            As[ak * 36 + am] = aval;
            Bs[(bk4 + 0) * 136 + bn_] = bv.x; Bs[(bk4 + 1) * 136 + bn_] = bv.y;
            Bs[(bk4 + 2) * 136 + bn_] = bv.z; Bs[(bk4 + 3) * 136 + bn_] = bv.w;
            __syncthreads();
            #pragma unroll
            for (int kk = 0; kk < 8; ++kk) {
                float4 av  = *(const float4*)&As[kk * 36 + ty * 4];
                float4 bv4 = *(const float4*)&Bs[kk * 136 + tx * 4];
                float a[4] = {av.x, av.y, av.z, av.w};
                float b[4] = {bv4.x, bv4.y, bv4.z, bv4.w};
                #pragma unroll
                for (int i = 0; i < 4; ++i)
                    #pragma unroll
                    for (int j = 0; j < 4; ++j)
                        acc[i][j] += a[i] * b[j];
            }
        }

        if (isV) {
            #pragma unroll
            for (int i = 0; i < 4; ++i) {
                const int m = ty * 4 + i;
                #pragma unroll
                for (int j = 0; j < 4; ++j) {
                    const int n = tx * 4 + j;
                    Ct[m * 133 + n] = fmaxf(acc[i][j] + bias[n], 0.f);
                }
            }
            __syncthreads();
            for (int o = ty; o < 10; o += 8) {
                const int row = tx;
                float s = ab1s[o];
                const float* wr = &aw1s[o * 128];
                #pragma unroll 8
                for (int k = 0; k < 128; ++k) s += Ct[row * 133 + k] * wr[k];
                v1s[row * 12 + o] = fmaxf(s, 0.f);
            }
            __syncthreads();
            if (t < 32) {
                float vv[10];
                #pragma unroll
                for (int o = 0; o < 10; ++o) vv[o] = v1s[t * 12 + o];
                #pragma unroll
                for (int p = 0; p < 5; ++p) {
                    float s = ab2s[p];
                    #pragma unroll
                    for (int o = 0; o < 10; ++o) s += aw2s[p * 10 + o] * vv[o];
                    V2[(size_t)(m0 + t) * 8 + p] = fmaxf(s, 0.f);
                }
            }
        } else {
            #pragma unroll
            for (int i = 0; i < 4; ++i) {
                const int m = m0 + ty * 4 + i;
                float4 ov = make_float4(acc[i][0] + bias[tx * 4 + 0],
                                        acc[i][1] + bias[tx * 4 + 1],
                                        acc[i][2] + bias[tx * 4 + 2],
                                        acc[i][3] + bias[tx * 4 + 3]);
                *(float4*)(DTH + (size_t)m * CNN + tx * 4) = ov;
            }
        }
    }
    GBAR();

    const float alpha = alpha_p[0];

    for (int itx = 0; itx < 3; ++itx) {
        // ---------------- P3: attention partials ---------------------------
        {
            float* Ks = smem;                       // 256*8
            const int cx = bid & 31, ry = bid >> 5;
            const int j0 = cx * JC;
            {
                const float4* src = (const float4*)(V2 + (size_t)j0 * 8);
                float4* dst = (float4*)Ks;
                dst[t] = src[t]; dst[t + 256] = src[t + 256];
            }
            __syncthreads();
            const int r0 = ry * 512 + t;
            const int r1 = r0 + 256;
            float4 q0a = *(const float4*)(V2 + (size_t)r0 * 8);
            float  q0e = V2[(size_t)r0 * 8 + 4];
            float4 q1a = *(const float4*)(V2 + (size_t)r1 * 8);
            float  q1e = V2[(size_t)r1 * 8 + 4];
            float l0 = 0.f, l1 = 0.f;
            float a0[5] = {0,0,0,0,0}, a1[5] = {0,0,0,0,0};
            #pragma unroll 4
            for (int jj = 0; jj < JC; ++jj) {
                float4 k4 = *(const float4*)&Ks[jj * 8];
                float  k5 = Ks[jj * 8 + 4];
                float s0 = q0a.x*k4.x + q0a.y*k4.y + q0a.z*k4.z + q0a.w*k4.w + q0e*k5;
                float s1 = q1a.x*k4.x + q1a.y*k4.y + q1a.z*k4.z + q1a.w*k4.w + q1e*k5;
                float e0 = __expf(s0);
                float e1 = __expf(s1);
                l0 += e0; l1 += e1;
                a0[0] += e0*k4.x; a0[1] += e0*k4.y; a0[2] += e0*k4.z;
                a0[3] += e0*k4.w; a0[4] += e0*k5;
                a1[0] += e1*k4.x; a1[1] += e1*k4.y; a1[2] += e1*k4.z;
                a1[3] += e1*k4.w; a1[4] += e1*k5;
            }
            float* p0 = part + ((size_t)cx * NR + r0) * 8;
            float* p1 = part + ((size_t)cx * NR + r1) * 8;
            *(float4*)p0       = make_float4(a0[0], a0[1], a0[2], a0[3]);
            *(float2*)(p0 + 4) = make_float2(a0[4], l0);
            *(float4*)p1       = make_float4(a1[0], a1[1], a1[2], a1[3]);
            *(float2*)(p1 + 4) = make_float2(a1[4], l1);
        }
        GBAR();

        // ---------------- P4: merge + L3 (LDS) + iter GEMM + epilogue ------
        {
            float* w4s  = smem;          // 1280
            float* aw1t = smem + 1280;   // 1280, transposed [k*10+o]
            float* b4s  = smem + 2560;   // 128
            float* bds  = smem + 2688;   // 128
            float* aw2s = smem + 2816;   // 50
            float* ab1s = smem + 2880;   // 10
            float* ab2s = smem + 2896;   // 5
            float* w3s  = smem + 2912;   // 50
            float* b3s  = smem + 2976;   // 10
            float* v4s  = smem + 2992;   // [16][12]
            float* As   = smem + 3200;   // [8][20]
            float* Bs   = smem + 3392;   // [8][136]
            float* Ct   = smem + 4480;   // [16][133]
            float* v1s  = smem + 6624;   // [16][12]

            const int m0 = bid * 16;
            for (int i = t; i < 1280; i += 256) {
                w4s[i] = aw4[i];
                const int o = i >> 7, k = i & 127;
                aw1t[k * 10 + o] = aw1[i];
            }
            if (t < 128) { b4s[t] = ab4[t]; bds[t] = bdtd[t]; }
            if (t < 50)  { aw2s[t] = aw2[t]; w3s[t] = aw3[t]; }
            if (t < 10)  { ab1s[t] = ab1[t]; b3s[t] = ab3[t]; }
            if (t < 5)   ab2s[t] = ab2[t];
            __syncthreads();

            // merge head: v4 for the block's 16 rows
            {
                const int row = t >> 4, sub = t & 15;
                const int r = m0 + row;
                float a0=0.f,a1=0.f,a2=0.f,a3=0.f,a4=0.f,l=0.f;
                #pragma unroll
                for (int cc = 0; cc < 2; ++cc) {
                    const int c = sub * 2 + cc;
                    const float* p = part + ((size_t)c * NR + r) * 8;
                    float4 x = *(const float4*)p;
                    float2 y = *(const float2*)(p + 4);
                    a0 += x.x; a1 += x.y; a2 += x.z; a3 += x.w; a4 += y.x; l += y.y;
                }
                #pragma unroll
                for (int m = 1; m < 16; m <<= 1) {
                    a0 += __shfl_xor(a0, m); a1 += __shfl_xor(a1, m);
                    a2 += __shfl_xor(a2, m); a3 += __shfl_xor(a3, m);
                    a4 += __shfl_xor(a4, m); l  += __shfl_xor(l,  m);
                }
                if (sub == 0) {
                    const float inv = 1.f / l;
                    float av[5] = {a0*inv, a1*inv, a2*inv, a3*inv, a4*inv};
                    #pragma unroll
                    for (int o = 0; o < 10; ++o) {
                        float s = b3s[o];
                        #pragma unroll
                        for (int c = 0; c < 5; ++c) s += w3s[o * 5 + c] * av[c];
                        v4s[row * 12 + o] = fmaxf(s, 0.f);
                    }
                }
            }
            __syncthreads();

            const int am = t >> 3, ak = t & 7;        // t<128 stages A
            float v4r[10];
            if (t < 128) {
                #pragma unroll
                for (int o = 0; o < 10; ++o) v4r[o] = v4s[am * 12 + o];
            }
            const int bn_ = t >> 1, bk4 = (t & 1) * 4;
            const float* brow = wdtd + (size_t)bn_ * CNN + bk4;
            const float* arow = DTH + (size_t)(m0 + am) * CNN;
            const int tx = t & 31, ty = t >> 5;
            float acc[2][4] = {};

            for (int k0 = 0; k0 < CNN; k0 += 8) {
                float aval = 0.f;
                float4 bv = *(const float4*)(brow + k0);
                if (t < 128) {
                    const int k = k0 + ak;
                    float pre = b4s[k];
                    #pragma unroll
                    for (int o = 0; o < 10; ++o) pre += w4s[k * 10 + o] * v4r[o];
                    aval = arow[k0 + ak] + alpha * fmaxf(pre, 0.f);
                }
                __syncthreads();
                if (t < 128) As[ak * 20 + am] = aval;
                Bs[(bk4 + 0) * 136 + bn_] = bv.x; Bs[(bk4 + 1) * 136 + bn_] = bv.y;
                Bs[(bk4 + 2) * 136 + bn_] = bv.z; Bs[(bk4 + 3) * 136 + bn_] = bv.w;
                __syncthreads();
                #pragma unroll
                for (int kk = 0; kk < 8; ++kk) {
                    float2 av  = *(const float2*)&As[kk * 20 + ty * 2];
                    float4 bv4 = *(const float4*)&Bs[kk * 136 + tx * 4];
                    float a[2] = {av.x, av.y};
                    float b[4] = {bv4.x, bv4.y, bv4.z, bv4.w};
                    #pragma unroll
                    for (int i = 0; i < 2; ++i)
                        #pragma unroll
                        for (int j = 0; j < 4; ++j)
                            acc[i][j] += a[i] * b[j];
                }
            }

            if (itx < 2) {
                #pragma unroll
                for (int i = 0; i < 2; ++i) {
                    const int m = ty * 2 + i;
                    #pragma unroll
                    for (int j = 0; j < 4; ++j) {
                        const int n = tx * 4 + j;
                        Ct[m * 133 + n] = fmaxf(acc[i][j] + bds[n], 0.f);
                    }
                }
                __syncthreads();
                if (t < 160) {
                    const int row = t / 10, o = t % 10;
                    float s = ab1s[o];
                    #pragma unroll 8
                    for (int k = 0; k < 128; ++k) s += Ct[row * 133 + k] * aw1t[k * 10 + o];
                    v1s[row * 12 + o] = fmaxf(s, 0.f);
                }
                __syncthreads();
                if (t < 16) {
                    float vv[10];
                    #pragma unroll
                    for (int o = 0; o < 10; ++o) vv[o] = v1s[t * 12 + o];
                    #pragma unroll
                    for (int p = 0; p < 5; ++p) {
                        float s = ab2s[p];
                        #pragma unroll
                        for (int o = 0; o < 10; ++o) s += aw2s[p * 10 + o] * vv[o];
                        V2[(size_t)(m0 + t) * 8 + p] = fmaxf(s, 0.f);
                    }
                }
            } else {
                #pragma unroll
                for (int i = 0; i < 2; ++i) {
                    const int m = m0 + ty * 2 + i;
                    float4 ov = make_float4(fmaxf(acc[i][0] + bds[tx * 4 + 0], 0.f),
                                            fmaxf(acc[i][1] + bds[tx * 4 + 1], 0.f),
                                            fmaxf(acc[i][2] + bds[tx * 4 + 2], 0.f),
                                            fmaxf(acc[i][3] + bds[tx * 4 + 3], 0.f));
                    *(float4*)(outV + (size_t)m * CNN + tx * 4) = ov;
                }
            }
        }
        GBAR();
    }

    // ---------------- P5: H_R = V @ wdt -----------------------------------
    {
        float* As = smem;          // [8][68]
        float* Bs = smem + 544;    // [8][68]
        const int m0 = (bid >> 2) * 64;
        const int n0 = (bid & 3) * 64;
        const int tx = t & 15, ty = t >> 4;
        const int lm = t >> 2, lk = (t & 3) * 2;
        const int bkk = t >> 5, bnn = (t & 31) * 2;
        float acc[4][4] = {};
        for (int k0 = 0; k0 < CNN; k0 += 8) {
            float2 a2 = *(const float2*)(outV + (size_t)(m0 + lm) * CNN + k0 + lk);
            float2 w2 = make_float2(0.f, 0.f);
            if (n0 + bnn < CIN)
                w2 = *(const float2*)(wdt + (size_t)(k0 + bkk) * CIN + n0 + bnn);
            __syncthreads();
            As[(lk + 0) * 68 + lm] = a2.x;
            As[(lk + 1) * 68 + lm] = a2.y;
            Bs[bkk * 68 + bnn]     = w2.x;
            Bs[bkk * 68 + bnn + 1] = w2.y;
            __syncthreads();
            #pragma unroll
            for (int kk = 0; kk < 8; ++kk) {
                float a[4], b[4];
                #pragma unroll
                for (int i = 0; i < 4; ++i) a[i] = As[kk * 68 + ty * 4 + i];
                #pragma unroll
                for (int j = 0; j < 4; ++j) b[j] = Bs[kk * 68 + tx * 4 + j];
                #pragma unroll
                for (int i = 0; i < 4; ++i)
                    #pragma unroll
                    for (int j = 0; j < 4; ++j)
                        acc[i][j] += a[i] * b[j];
            }
        }
        #pragma unroll
        for (int i = 0; i < 4; ++i) {
            const int m = m0 + ty * 4 + i;
            #pragma unroll
            for (int j = 0; j < 4; ++j) {
                const int n = n0 + tx * 4 + j;
                if (n < CIN) outHR[(size_t)m * CIN + n] = acc[i][j];
            }
        }
    }
}

// --------------------------------------------------------------- launcher
extern "C" void kernel_launch(void* const* d_in, const int* in_sizes, int n_in,
                              void* d_out, int out_size, void* d_ws, size_t ws_size,
                              hipStream_t stream)
{
    (void)in_sizes; (void)n_in; (void)out_size; (void)ws_size;
    const float* H     = (const float*)d_in[0];
    const float* alpha = (const float*)d_in[1];
    const float* gamma = (const float*)d_in[2];
    const float* beta  = (const float*)d_in[3];
    const float* w1    = (const float*)d_in[4];
    const float* b1    = (const float*)d_in[5];
    const float* wdt   = (const float*)d_in[6];
    const float* bdt   = (const float*)d_in[7];
    const float* wdtd  = (const float*)d_in[8];
    const float* bdtd  = (const float*)d_in[9];
    const float* aw1   = (const float*)d_in[10];
    const float* ab1   = (const float*)d_in[11];
    const float* aw2   = (const float*)d_in[12];
    const float* ab2   = (const float*)d_in[13];
    const float* aw3   = (const float*)d_in[14];
    const float* ab3   = (const float*)d_in[15];
    const float* aw4   = (const float*)d_in[16];
    const float* ab4   = (const float*)d_in[17];

    float* ws    = (float*)d_ws;
    float* outV  = (float*)d_out;
    float* outHR = outV + (size_t)NR * CNN;

    hipMemsetAsync(d_ws, 0, 64, stream);   // barrier counter
    mega_k<<<NBLK, 256, 0, stream>>>(H, alpha, gamma, beta, w1, b1, wdt, bdt,
                                     wdtd, bdtd, aw1, ab1, aw2, ab2, aw3, ab3,
                                     aw4, ab4, ws, outV, outHR);
}

// Round 5
// 434.511 us; speedup vs baseline: 1.6136x; 1.6136x over previous
//
#include <hip/hip_runtime.h>
#include <hip/hip_bf16.h>

#define NR   8192
#define CIN  200
#define CNN  128
#define NCH  32
#define JC   256
#define BN_EPS 1e-5f
#define NBLK 512

// ws float offsets
#define OFF_BNPART 64                        // 64 blocks * 400
#define OFF_DTH    (OFF_BNPART + 64 * 400)
#define OFF_V2     (OFF_DTH + NR * CNN)
#define OFF_PART   (OFF_V2 + NR * 8)

// grid barrier: all NBLK blocks co-resident (launch_bounds(256,2), LDS 48KB -> 2-3 blocks/CU)
// RELAXED polling (no per-poll cache maintenance!) + one release/acquire fence pair.
#define GBAR() do {                                                              \
    __syncthreads();                                                             \
    if (t == 0) {                                                                \
        __builtin_amdgcn_fence(__ATOMIC_RELEASE, "agent");                       \
        ++ep;                                                                    \
        __hip_atomic_fetch_add(bar, 1u, __ATOMIC_RELAXED, __HIP_MEMORY_SCOPE_AGENT); \
        const unsigned tgt = (unsigned)ep * NBLK;                                \
        while (__hip_atomic_load(bar, __ATOMIC_RELAXED, __HIP_MEMORY_SCOPE_AGENT) < tgt) \
            __builtin_amdgcn_s_sleep(16);                                        \
        __builtin_amdgcn_fence(__ATOMIC_ACQUIRE, "agent");                       \
    }                                                                            \
    __syncthreads();                                                             \
} while (0)

__global__ __launch_bounds__(256, 2) void mega_k(
    const float* __restrict__ H,    const float* __restrict__ alpha_p,
    const float* __restrict__ gamma,const float* __restrict__ beta,
    const float* __restrict__ w1,   const float* __restrict__ b1,
    const float* __restrict__ wdt,  const float* __restrict__ bdt,
    const float* __restrict__ wdtd, const float* __restrict__ bdtd,
    const float* __restrict__ aw1,  const float* __restrict__ ab1,
    const float* __restrict__ aw2,  const float* __restrict__ ab2,
    const float* __restrict__ aw3,  const float* __restrict__ ab3,
    const float* __restrict__ aw4,  const float* __restrict__ ab4,
    float* __restrict__ ws, float* __restrict__ outV, float* __restrict__ outHR)
{
    __shared__ float4 smem4[3072];            // 48 KB
    float* smem = (float*)smem4;

    unsigned* bar = (unsigned*)ws;
    float* bnpart = ws + OFF_BNPART;
    float* DTH    = ws + OFF_DTH;
    float* V2     = ws + OFF_V2;
    float* part   = ws + OFF_PART;

    const int bid = blockIdx.x;
    const int t   = threadIdx.x;
    int ep = 0;

    // ---------------- P0: BN partial sums (64 blocks x 128 rows) ----------
    if (bid < 64 && t < CIN) {
        const float* p = H + (size_t)bid * 128 * CIN + t;
        float s = 0.f, q = 0.f;
        #pragma unroll 8
        for (int r = 0; r < 128; ++r) { float v = p[(size_t)r * CIN]; s += v; q += v * v; }
        bnpart[bid * 400 + t]       = s;
        bnpart[bid * 400 + 200 + t] = q;
    }
    GBAR();

    // ---------------- P2: BN finalize (per-block) + dual GEMM -------------
    {
        float* scs  = smem;          // 256
        float* shs  = smem + 256;    // 256
        float* bias = smem + 512;    // 128
        float* aw1s = smem + 768;    // 1280
        float* aw2s = smem + 2048;   // 50
        float* ab1s = smem + 2112;   // 10
        float* ab2s = smem + 2128;   // 5
        float* As   = smem + 2144;   // [8][36]
        float* Bs   = smem + 2432;   // [8][136]
        float* Ct   = smem + 3520;   // [32][133]
        float* v1s  = smem + 7776;   // [32][12]

        const bool isV = (bid < 256);
        const int  m0  = (bid & 255) * 32;

        if (t < CIN) {
            float s = 0.f, q = 0.f;
            const float* p = bnpart + t;
            #pragma unroll 8
            for (int b = 0; b < 64; ++b) { s += p[b * 400]; q += p[b * 400 + 200]; }
            float mu  = s * (1.f / NR);
            float var = q * (1.f / NR) - mu * mu;
            float sc  = rsqrtf(var + BN_EPS) * gamma[t];
            scs[t] = sc; shs[t] = beta[t] - mu * sc;
        }
        if (t < CNN) bias[t] = isV ? b1[t] : bdt[t];
        if (isV) {
            for (int i = t; i < 1280; i += 256) aw1s[i] = aw1[i];
            if (t < 50) aw2s[t] = aw2[t];
            if (t < 10) ab1s[t] = ab1[t];
            if (t < 5)  ab2s[t] = ab2[t];
        }
        const int am = t >> 3, ak = t & 7;
        const int bn_ = t >> 1, bk4 = (t & 1) * 4;
        const float* brow = (isV ? w1 : wdt) + (size_t)bn_ * CIN + bk4;
        const float* arow = H + (size_t)(m0 + am) * CIN + ak;
        const int tx = t & 31, ty = t >> 5;
        float acc[4][4] = {};
        __syncthreads();

        for (int k0 = 0; k0 < CIN; k0 += 8) {
            const int k = k0 + ak;
            float  aval = arow[k0] * scs[k] + shs[k];
            float4 bv   = *(const float4*)(brow + k0);
            __syncthreads();
            As[ak * 36 + am] = aval;
            Bs[(bk4 + 0) * 136 + bn_] = bv.x; Bs[(bk4 + 1) * 136 + bn_] = bv.y;
            Bs[(bk4 + 2) * 136 + bn_] = bv.z; Bs[(bk4 + 3) * 136 + bn_] = bv.w;
            __syncthreads();
            #pragma unroll
            for (int kk = 0; kk < 8; ++kk) {
                float4 av  = *(const float4*)&As[kk * 36 + ty * 4];
                float4 bv4 = *(const float4*)&Bs[kk * 136 + tx * 4];
                float a[4] = {av.x, av.y, av.z, av.w};
                float b[4] = {bv4.x, bv4.y, bv4.z, bv4.w};
                #pragma unroll
                for (int i = 0; i < 4; ++i)
                    #pragma unroll
                    for (int j = 0; j < 4; ++j)
                        acc[i][j] += a[i] * b[j];
            }
        }

        if (isV) {
            #pragma unroll
            for (int i = 0; i < 4; ++i) {
                const int m = ty * 4 + i;
                #pragma unroll
                for (int j = 0; j < 4; ++j) {
                    const int n = tx * 4 + j;
                    Ct[m * 133 + n] = fmaxf(acc[i][j] + bias[n], 0.f);
                }
            }
            __syncthreads();
            for (int o = ty; o < 10; o += 8) {
                const int row = tx;
                float s = ab1s[o];
                const float* wr = &aw1s[o * 128];
                #pragma unroll 8
                for (int k = 0; k < 128; ++k) s += Ct[row * 133 + k] * wr[k];
                v1s[row * 12 + o] = fmaxf(s, 0.f);
            }
            __syncthreads();
            if (t < 32) {
                float vv[10];
                #pragma unroll
                for (int o = 0; o < 10; ++o) vv[o] = v1s[t * 12 + o];
                #pragma unroll
                for (int p = 0; p < 5; ++p) {
                    float s = ab2s[p];
                    #pragma unroll
                    for (int o = 0; o < 10; ++o) s += aw2s[p * 10 + o] * vv[o];
                    V2[(size_t)(m0 + t) * 8 + p] = fmaxf(s, 0.f);
                }
            }
        } else {
            #pragma unroll
            for (int i = 0; i < 4; ++i) {
                const int m = m0 + ty * 4 + i;
                float4 ov = make_float4(acc[i][0] + bias[tx * 4 + 0],
                                        acc[i][1] + bias[tx * 4 + 1],
                                        acc[i][2] + bias[tx * 4 + 2],
                                        acc[i][3] + bias[tx * 4 + 3]);
                *(float4*)(DTH + (size_t)m * CNN + tx * 4) = ov;
            }
        }
    }
    GBAR();

    const float alpha = alpha_p[0];

    for (int itx = 0; itx < 3; ++itx) {
        // ---------------- P3: attention partials ---------------------------
        {
            float* Ks = smem;                       // 256*8
            const int cx = bid & 31, ry = bid >> 5;
            const int j0 = cx * JC;
            {
                const float4* src = (const float4*)(V2 + (size_t)j0 * 8);
                float4* dst = (float4*)Ks;
                dst[t] = src[t]; dst[t + 256] = src[t + 256];
            }
            __syncthreads();
            const int r0 = ry * 512 + t;
            const int r1 = r0 + 256;
            float4 q0a = *(const float4*)(V2 + (size_t)r0 * 8);
            float  q0e = V2[(size_t)r0 * 8 + 4];
            float4 q1a = *(const float4*)(V2 + (size_t)r1 * 8);
            float  q1e = V2[(size_t)r1 * 8 + 4];
            float l0 = 0.f, l1 = 0.f;
            float a0[5] = {0,0,0,0,0}, a1[5] = {0,0,0,0,0};
            #pragma unroll 4
            for (int jj = 0; jj < JC; ++jj) {
                float4 k4 = *(const float4*)&Ks[jj * 8];
                float  k5 = Ks[jj * 8 + 4];
                float s0 = q0a.x*k4.x + q0a.y*k4.y + q0a.z*k4.z + q0a.w*k4.w + q0e*k5;
                float s1 = q1a.x*k4.x + q1a.y*k4.y + q1a.z*k4.z + q1a.w*k4.w + q1e*k5;
                float e0 = __expf(s0);
                float e1 = __expf(s1);
                l0 += e0; l1 += e1;
                a0[0] += e0*k4.x; a0[1] += e0*k4.y; a0[2] += e0*k4.z;
                a0[3] += e0*k4.w; a0[4] += e0*k5;
                a1[0] += e1*k4.x; a1[1] += e1*k4.y; a1[2] += e1*k4.z;
                a1[3] += e1*k4.w; a1[4] += e1*k5;
            }
            float* p0 = part + ((size_t)cx * NR + r0) * 8;
            float* p1 = part + ((size_t)cx * NR + r1) * 8;
            *(float4*)p0       = make_float4(a0[0], a0[1], a0[2], a0[3]);
            *(float2*)(p0 + 4) = make_float2(a0[4], l0);
            *(float4*)p1       = make_float4(a1[0], a1[1], a1[2], a1[3]);
            *(float2*)(p1 + 4) = make_float2(a1[4], l1);
        }
        GBAR();

        // ---------------- P4: merge + L3 (LDS) + iter GEMM + epilogue ------
        {
            float* w4s  = smem;          // 1280
            float* aw1t = smem + 1280;   // 1280, transposed [k*10+o]
            float* b4s  = smem + 2560;   // 128
            float* bds  = smem + 2688;   // 128
            float* aw2s = smem + 2816;   // 50
            float* ab1s = smem + 2880;   // 10
            float* ab2s = smem + 2896;   // 5
            float* w3s  = smem + 2912;   // 50
            float* b3s  = smem + 2976;   // 10
            float* v4s  = smem + 2992;   // [16][12]
            float* As   = smem + 3200;   // [8][20]
            float* Bs   = smem + 3392;   // [8][136]
            float* Ct   = smem + 4480;   // [16][133]
            float* v1s  = smem + 6624;   // [16][12]

            const int m0 = bid * 16;
            for (int i = t; i < 1280; i += 256) {
                w4s[i] = aw4[i];
                const int o = i >> 7, k = i & 127;
                aw1t[k * 10 + o] = aw1[i];
            }
            if (t < 128) { b4s[t] = ab4[t]; bds[t] = bdtd[t]; }
            if (t < 50)  { aw2s[t] = aw2[t]; w3s[t] = aw3[t]; }
            if (t < 10)  { ab1s[t] = ab1[t]; b3s[t] = ab3[t]; }
            if (t < 5)   ab2s[t] = ab2[t];
            __syncthreads();

            // merge head: v4 for the block's 16 rows
            {
                const int row = t >> 4, sub = t & 15;
                const int r = m0 + row;
                float a0=0.f,a1=0.f,a2=0.f,a3=0.f,a4=0.f,l=0.f;
                #pragma unroll
                for (int cc = 0; cc < 2; ++cc) {
                    const int c = sub * 2 + cc;
                    const float* p = part + ((size_t)c * NR + r) * 8;
                    float4 x = *(const float4*)p;
                    float2 y = *(const float2*)(p + 4);
                    a0 += x.x; a1 += x.y; a2 += x.z; a3 += x.w; a4 += y.x; l += y.y;
                }
                #pragma unroll
                for (int m = 1; m < 16; m <<= 1) {
                    a0 += __shfl_xor(a0, m); a1 += __shfl_xor(a1, m);
                    a2 += __shfl_xor(a2, m); a3 += __shfl_xor(a3, m);
                    a4 += __shfl_xor(a4, m); l  += __shfl_xor(l,  m);
                }
                if (sub == 0) {
                    const float inv = 1.f / l;
                    float av[5] = {a0*inv, a1*inv, a2*inv, a3*inv, a4*inv};
                    #pragma unroll
                    for (int o = 0; o < 10; ++o) {
                        float s = b3s[o];
                        #pragma unroll
                        for (int c = 0; c < 5; ++c) s += w3s[o * 5 + c] * av[c];
                        v4s[row * 12 + o] = fmaxf(s, 0.f);
                    }
                }
            }
            __syncthreads();

            const int am = t >> 3, ak = t & 7;        // t<128 stages A
            float v4r[10];
            if (t < 128) {
                #pragma unroll
                for (int o = 0; o < 10; ++o) v4r[o] = v4s[am * 12 + o];
            }
            const int bn_ = t >> 1, bk4 = (t & 1) * 4;
            const float* brow = wdtd + (size_t)bn_ * CNN + bk4;
            const float* arow = DTH + (size_t)(m0 + am) * CNN;
            const int tx = t & 31, ty = t >> 5;
            float acc[2][4] = {};

            for (int k0 = 0; k0 < CNN; k0 += 8) {
                float aval = 0.f;
                float4 bv = *(const float4*)(brow + k0);
                if (t < 128) {
                    const int k = k0 + ak;
                    float pre = b4s[k];
                    #pragma unroll
                    for (int o = 0; o < 10; ++o) pre += w4s[k * 10 + o] * v4r[o];
                    aval = arow[k0 + ak] + alpha * fmaxf(pre, 0.f);
                }
                __syncthreads();
                if (t < 128) As[ak * 20 + am] = aval;
                Bs[(bk4 + 0) * 136 + bn_] = bv.x; Bs[(bk4 + 1) * 136 + bn_] = bv.y;
                Bs[(bk4 + 2) * 136 + bn_] = bv.z; Bs[(bk4 + 3) * 136 + bn_] = bv.w;
                __syncthreads();
                #pragma unroll
                for (int kk = 0; kk < 8; ++kk) {
                    float2 av  = *(const float2*)&As[kk * 20 + ty * 2];
                    float4 bv4 = *(const float4*)&Bs[kk * 136 + tx * 4];
                    float a[2] = {av.x, av.y};
                    float b[4] = {bv4.x, bv4.y, bv4.z, bv4.w};
                    #pragma unroll
                    for (int i = 0; i < 2; ++i)
                        #pragma unroll
                        for (int j = 0; j < 4; ++j)
                            acc[i][j] += a[i] * b[j];
                }
            }

            if (itx < 2) {
                #pragma unroll
                for (int i = 0; i < 2; ++i) {
                    const int m = ty * 2 + i;
                    #pragma unroll
                    for (int j = 0; j < 4; ++j) {
                        const int n = tx * 4 + j;
                        Ct[m * 133 + n] = fmaxf(acc[i][j] + bds[n], 0.f);
                    }
                }
                __syncthreads();
                if (t < 160) {
                    const int row = t / 10, o = t % 10;
                    float s = ab1s[o];
                    #pragma unroll 8
                    for (int k = 0; k < 128; ++k) s += Ct[row * 133 + k] * aw1t[k * 10 + o];
                    v1s[row * 12 + o] = fmaxf(s, 0.f);
                }
                __syncthreads();
                if (t < 16) {
                    float vv[10];
                    #pragma unroll
                    for (int o = 0; o < 10; ++o) vv[o] = v1s[t * 12 + o];
                    #pragma unroll
                    for (int p = 0; p < 5; ++p) {
                        float s = ab2s[p];
                        #pragma unroll
                        for (int o = 0; o < 10; ++o) s += aw2s[p * 10 + o] * vv[o];
                        V2[(size_t)(m0 + t) * 8 + p] = fmaxf(s, 0.f);
                    }
                }
            } else {
                #pragma unroll
                for (int i = 0; i < 2; ++i) {
                    const int m = m0 + ty * 2 + i;
                    float4 ov = make_float4(fmaxf(acc[i][0] + bds[tx * 4 + 0], 0.f),
                                            fmaxf(acc[i][1] + bds[tx * 4 + 1], 0.f),
                                            fmaxf(acc[i][2] + bds[tx * 4 + 2], 0.f),
                                            fmaxf(acc[i][3] + bds[tx * 4 + 3], 0.f));
                    *(float4*)(outV + (size_t)m * CNN + tx * 4) = ov;
                }
            }
        }
        GBAR();
    }

    // ---------------- P5: H_R = V @ wdt -----------------------------------
    {
        float* As = smem;          // [8][68]
        float* Bs = smem + 544;    // [8][68]
        const int m0 = (bid >> 2) * 64;
        const int n0 = (bid & 3) * 64;
        const int tx = t & 15, ty = t >> 4;
        const int lm = t >> 2, lk = (t & 3) * 2;
        const int bkk = t >> 5, bnn = (t & 31) * 2;
        float acc[4][4] = {};
        for (int k0 = 0; k0 < CNN; k0 += 8) {
            float2 a2 = *(const float2*)(outV + (size_t)(m0 + lm) * CNN + k0 + lk);
            float2 w2 = make_float2(0.f, 0.f);
            if (n0 + bnn < CIN)
                w2 = *(const float2*)(wdt + (size_t)(k0 + bkk) * CIN + n0 + bnn);
            __syncthreads();
            As[(lk + 0) * 68 + lm] = a2.x;
            As[(lk + 1) * 68 + lm] = a2.y;
            Bs[bkk * 68 + bnn]     = w2.x;
            Bs[bkk * 68 + bnn + 1] = w2.y;
            __syncthreads();
            #pragma unroll
            for (int kk = 0; kk < 8; ++kk) {
                float a[4], b[4];
                #pragma unroll
                for (int i = 0; i < 4; ++i) a[i] = As[kk * 68 + ty * 4 + i];
                #pragma unroll
                for (int j = 0; j < 4; ++j) b[j] = Bs[kk * 68 + tx * 4 + j];
                #pragma unroll
                for (int i = 0; i < 4; ++i)
                    #pragma unroll
                    for (int j = 0; j < 4; ++j)
                        acc[i][j] += a[i] * b[j];
            }
        }
        #pragma unroll
        for (int i = 0; i < 4; ++i) {
            const int m = m0 + ty * 4 + i;
            #pragma unroll
            for (int j = 0; j < 4; ++j) {
                const int n = n0 + tx * 4 + j;
                if (n < CIN) outHR[(size_t)m * CIN + n] = acc[i][j];
            }
        }
    }
}

// --------------------------------------------------------------- launcher
extern "C" void kernel_launch(void* const* d_in, const int* in_sizes, int n_in,
                              void* d_out, int out_size, void* d_ws, size_t ws_size,
                              hipStream_t stream)
{
    (void)in_sizes; (void)n_in; (void)out_size; (void)ws_size;
    const float* H     = (const float*)d_in[0];
    const float* alpha = (const float*)d_in[1];
    const float* gamma = (const float*)d_in[2];
    const float* beta  = (const float*)d_in[3];
    const float* w1    = (const float*)d_in[4];
    const float* b1    = (const float*)d_in[5];
    const float* wdt   = (const float*)d_in[6];
    const float* bdt   = (const float*)d_in[7];
    const float* wdtd  = (const float*)d_in[8];
    const float* bdtd  = (const float*)d_in[9];
    const float* aw1   = (const float*)d_in[10];
    const float* ab1   = (const float*)d_in[11];
    const float* aw2   = (const float*)d_in[12];
    const float* ab2   = (const float*)d_in[13];
    const float* aw3   = (const float*)d_in[14];
    const float* ab3   = (const float*)d_in[15];
    const float* aw4   = (const float*)d_in[16];
    const float* ab4   = (const float*)d_in[17];

    float* ws    = (float*)d_ws;
    float* outV  = (float*)d_out;
    float* outHR = outV + (size_t)NR * CNN;

    hipMemsetAsync(d_ws, 0, 64, stream);   // barrier counter
    mega_k<<<NBLK, 256, 0, stream>>>(H, alpha, gamma, beta, w1, b1, wdt, bdt,
                                     wdtd, bdtd, aw1, ab1, aw2, ab2, aw3, ab3,
                                     aw4, ab4, ws, outV, outHR);
}

// Round 6
// 208.485 us; speedup vs baseline: 3.3629x; 2.0841x over previous
//
#include <hip/hip_runtime.h>
#include <hip/hip_bf16.h>

#define NR   8192
#define CIN  200
#define CNN  128
#define BN_EPS 1e-5f

// ws float offsets
#define OFF_BNPART 0                          // 64 blocks * 400
#define OFF_DTH    (OFF_BNPART + 64 * 400)
#define OFF_V2A    (OFF_DTH + NR * CNN)
#define OFF_V2B    (OFF_V2A + NR * 8)

// ---------------- BN pass 1: row-block partial sums ------------------------
__global__ __launch_bounds__(256) void bn1_k(
    const float* __restrict__ H, float* __restrict__ ws)
{
    const int t = threadIdx.x;
    if (t >= CIN) return;
    const float* p = H + (size_t)blockIdx.x * 128 * CIN + t;
    float s = 0.f, q = 0.f;
    #pragma unroll 8
    for (int r = 0; r < 128; ++r) { float v = p[(size_t)r * CIN]; s += v; q += v * v; }
    ws[OFF_BNPART + blockIdx.x * 400 + t]       = s;
    ws[OFF_BNPART + blockIdx.x * 400 + 200 + t] = q;
}

// ---------------- BN finalize (per block) + dual GEMM + l12 epilogue -------
// bid<256: V tile rows bid*32 (relu +b1, then aenet L1+L2 -> V2a); else DTH.
__global__ __launch_bounds__(256) void gemm_bn_k(
    const float* __restrict__ H, const float* __restrict__ w1,
    const float* __restrict__ b1, const float* __restrict__ wdt,
    const float* __restrict__ bdt,
    const float* __restrict__ aw1, const float* __restrict__ ab1,
    const float* __restrict__ aw2, const float* __restrict__ ab2,
    const float* __restrict__ gamma, const float* __restrict__ beta,
    float* __restrict__ ws, float* __restrict__ DTH, float* __restrict__ V2)
{
    __shared__ float smem[8192];
    float* scs  = smem;          // 256
    float* shs  = smem + 256;    // 256
    float* bias = smem + 512;    // 128
    float* aw1s = smem + 768;    // 1280
    float* aw2s = smem + 2048;   // 64
    float* ab1s = smem + 2112;   // 16
    float* ab2s = smem + 2128;   // 16
    float* As   = smem + 2144;   // [8][36]
    float* Bs   = smem + 2432;   // [8][136]
    float* Ct   = smem + 3520;   // [32][133]
    float* v1s  = smem + 7776;   // [32][12]

    const int t   = threadIdx.x;
    const int bid = blockIdx.x;
    const bool isV = (bid < 256);
    const int  m0  = (bid & 255) * 32;
    const float* bnpart = ws + OFF_BNPART;

    if (t < CIN) {
        float s = 0.f, q = 0.f;
        const float* p = bnpart + t;
        #pragma unroll 8
        for (int b = 0; b < 64; ++b) { s += p[b * 400]; q += p[b * 400 + 200]; }
        float mu  = s * (1.f / NR);
        float var = q * (1.f / NR) - mu * mu;
        float sc  = rsqrtf(var + BN_EPS) * gamma[t];
        scs[t] = sc; shs[t] = beta[t] - mu * sc;
    }
    if (t < CNN) bias[t] = isV ? b1[t] : bdt[t];
    if (isV) {
        for (int i = t; i < 1280; i += 256) aw1s[i] = aw1[i];
        if (t < 50) aw2s[t] = aw2[t];
        if (t < 10) ab1s[t] = ab1[t];
        if (t < 5)  ab2s[t] = ab2[t];
    }
    const int am = t >> 3, ak = t & 7;
    const int bn_ = t >> 1, bk4 = (t & 1) * 4;
    const float* brow = (isV ? w1 : wdt) + (size_t)bn_ * CIN + bk4;
    const float* arow = H + (size_t)(m0 + am) * CIN + ak;
    const int tx = t & 31, ty = t >> 5;
    float acc[4][4] = {};
    __syncthreads();

    for (int k0 = 0; k0 < CIN; k0 += 8) {
        const int k = k0 + ak;
        float  aval = arow[k0] * scs[k] + shs[k];
        float4 bv   = *(const float4*)(brow + k0);
        __syncthreads();
        As[ak * 36 + am] = aval;
        Bs[(bk4 + 0) * 136 + bn_] = bv.x; Bs[(bk4 + 1) * 136 + bn_] = bv.y;
        Bs[(bk4 + 2) * 136 + bn_] = bv.z; Bs[(bk4 + 3) * 136 + bn_] = bv.w;
        __syncthreads();
        #pragma unroll
        for (int kk = 0; kk < 8; ++kk) {
            float4 av  = *(const float4*)&As[kk * 36 + ty * 4];
            float4 bv4 = *(const float4*)&Bs[kk * 136 + tx * 4];
            float a[4] = {av.x, av.y, av.z, av.w};
            float b[4] = {bv4.x, bv4.y, bv4.z, bv4.w};
            #pragma unroll
            for (int i = 0; i < 4; ++i)
                #pragma unroll
                for (int j = 0; j < 4; ++j)
                    acc[i][j] += a[i] * b[j];
        }
    }

    if (isV) {
        #pragma unroll
        for (int i = 0; i < 4; ++i) {
            const int m = ty * 4 + i;
            #pragma unroll
            for (int j = 0; j < 4; ++j) {
                const int n = tx * 4 + j;
                Ct[m * 133 + n] = fmaxf(acc[i][j] + bias[n], 0.f);
            }
        }
        __syncthreads();
        for (int o = ty; o < 10; o += 8) {
            const int row = tx;
            float s = ab1s[o];
            const float* wr = &aw1s[o * 128];
            #pragma unroll 8
            for (int k = 0; k < 128; ++k) s += Ct[row * 133 + k] * wr[k];
            v1s[row * 12 + o] = fmaxf(s, 0.f);
        }
        __syncthreads();
        if (t < 32) {
            float vv[10];
            #pragma unroll
            for (int o = 0; o < 10; ++o) vv[o] = v1s[t * 12 + o];
            #pragma unroll
            for (int p = 0; p < 5; ++p) {
                float s = ab2s[p];
                #pragma unroll
                for (int o = 0; o < 10; ++o) s += aw2s[p * 10 + o] * vv[o];
                V2[(size_t)(m0 + t) * 8 + p] = fmaxf(s, 0.f);
            }
        }
    } else {
        #pragma unroll
        for (int i = 0; i < 4; ++i) {
            const int m = m0 + ty * 4 + i;
            float4 ov = make_float4(acc[i][0] + bias[tx * 4 + 0],
                                    acc[i][1] + bias[tx * 4 + 1],
                                    acc[i][2] + bias[tx * 4 + 2],
                                    acc[i][3] + bias[tx * 4 + 3]);
            *(float4*)(DTH + (size_t)m * CNN + tx * 4) = ov;
        }
    }
}

// ---------------- fused iteration: full attn + merge + L3 + L4 + GEMM ------
// 512 blocks x 16 rows. Flash attention over ALL 8192 keys (LDS-chunked),
// then v4, then A = DTH + alpha*relu(L4(v4)), C = relu(A@wdtd^T + b),
// epilogue: l12 -> V2out  (or outV + H_R when last).
__global__ __launch_bounds__(256, 2) void fused_iter_k(
    const float* __restrict__ V2in, float* __restrict__ V2out,
    const float* __restrict__ DTH,  const float* __restrict__ alpha_p,
    const float* __restrict__ wdtd, const float* __restrict__ bdtd,
    const float* __restrict__ aw4,  const float* __restrict__ ab4,
    const float* __restrict__ aw1,  const float* __restrict__ ab1,
    const float* __restrict__ aw2,  const float* __restrict__ ab2,
    const float* __restrict__ aw3,  const float* __restrict__ ab3,
    const float* __restrict__ wdt,
    float* __restrict__ outV, float* __restrict__ outHR)
{
    __shared__ float smem[11760];             // 47 KB
    float* Ks   = smem;          // 8192 (attn) ; GEMM reuses: As@0, Bs@160, Ct@1248
    float* w4s  = smem + 8192;   // 1280
    float* aw1t = smem + 9472;   // 1280 transposed [k*10+o]
    float* b4s  = smem + 10752;  // 128
    float* bds  = smem + 10880;  // 128
    float* w3s  = smem + 11008;  // 64
    float* b3s  = smem + 11072;  // 16
    float* ab1s = smem + 11088;  // 16
    float* aw2s = smem + 11104;  // 64
    float* ab2s = smem + 11168;  // 16
    float* v4s  = smem + 11184;  // 16*12
    float* wred = smem + 11376;  // 16 rows * 4 waves * 6

    const int t   = threadIdx.x;
    const int bid = blockIdx.x;
    const int m0  = bid * 16;
    const bool last = (outV != nullptr);

    // stage weights (region disjoint from Ks)
    for (int i = t; i < 1280; i += 256) {
        w4s[i] = aw4[i];
        const int o = i >> 7, k = i & 127;
        aw1t[k * 10 + o] = aw1[i];
    }
    if (t < 128) { b4s[t] = ab4[t]; bds[t] = bdtd[t]; }
    if (t < 50)  { w3s[t] = aw3[t]; aw2s[t] = aw2[t]; }
    if (t < 10)  { b3s[t] = ab3[t]; ab1s[t] = ab1[t]; }
    if (t < 5)   ab2s[t] = ab2[t];

    // ---- flash attention over all keys; row = t&15, jgroup = t>>4 ----
    const int row = t & 15, jg = t >> 4;
    const int r = m0 + row;
    const float* qp = V2in + (size_t)r * 8;
    const float q0 = qp[0], q1 = qp[1], q2 = qp[2], q3 = qp[3], q4 = qp[4];
    float a0 = 0.f, a1 = 0.f, a2 = 0.f, a3 = 0.f, a4 = 0.f, l = 0.f;

    for (int chunk = 0; chunk < 8; ++chunk) {
        __syncthreads();
        const float4* src = (const float4*)(V2in + (size_t)chunk * 1024 * 8);
        float4* dst = (float4*)Ks;
        #pragma unroll
        for (int i = 0; i < 8; ++i) dst[t + i * 256] = src[t + i * 256];
        __syncthreads();
        const float* kp = Ks + jg * 64 * 8;
        #pragma unroll 4
        for (int jj = 0; jj < 64; ++jj) {
            float4 k4 = *(const float4*)(kp + jj * 8);
            float  k5 = kp[jj * 8 + 4];
            float s = q0 * k4.x + q1 * k4.y + q2 * k4.z + q3 * k4.w + q4 * k5;
            float e = __expf(s);
            l  += e;
            a0 += e * k4.x; a1 += e * k4.y; a2 += e * k4.z;
            a3 += e * k4.w; a4 += e * k5;
        }
    }
    // reduce the 16 jgroups: xor 16,32 within wave, then 4 wave-partials via LDS
    #pragma unroll
    for (int m = 16; m <= 32; m <<= 1) {
        a0 += __shfl_xor(a0, m); a1 += __shfl_xor(a1, m);
        a2 += __shfl_xor(a2, m); a3 += __shfl_xor(a3, m);
        a4 += __shfl_xor(a4, m); l  += __shfl_xor(l,  m);
    }
    __syncthreads();                       // Ks reads done; safe to reuse smem@0 later
    if ((jg & 3) == 0) {
        float* wp = wred + row * 24 + (t >> 6) * 6;
        wp[0] = a0; wp[1] = a1; wp[2] = a2; wp[3] = a3; wp[4] = a4; wp[5] = l;
    }
    __syncthreads();
    if (t < 16) {
        float A0=0,A1=0,A2=0,A3=0,A4=0,L=0;
        #pragma unroll
        for (int w = 0; w < 4; ++w) {
            const float* wp = wred + t * 24 + w * 6;
            A0 += wp[0]; A1 += wp[1]; A2 += wp[2]; A3 += wp[3]; A4 += wp[4]; L += wp[5];
        }
        const float inv = 1.f / L;
        float av[5] = {A0*inv, A1*inv, A2*inv, A3*inv, A4*inv};
        #pragma unroll
        for (int o = 0; o < 10; ++o) {
            float s = b3s[o];
            #pragma unroll
            for (int c = 0; c < 5; ++c) s += w3s[o * 5 + c] * av[c];
            v4s[t * 12 + o] = fmaxf(s, 0.f);
        }
    }
    __syncthreads();

    // ---- GEMM: A[16x128] (L4 head) @ wdtd^T -> C[16x128] ----
    float* As = smem;          // [8][20]
    float* Bs = smem + 160;    // [8][136]
    float* Ct = smem + 1248;   // [16][133]
    const float alpha = alpha_p[0];
    const int am = t >> 3, ak = t & 7;
    float v4r[10];
    if (t < 128) {
        #pragma unroll
        for (int o = 0; o < 10; ++o) v4r[o] = v4s[am * 12 + o];
    }
    const int bn_ = t >> 1, bk4 = (t & 1) * 4;
    const float* brow = wdtd + (size_t)bn_ * CNN + bk4;
    const float* arow = DTH + (size_t)(m0 + am) * CNN;
    const int tx = t & 31, ty = t >> 5;
    float acc[2][4] = {};

    for (int k0 = 0; k0 < CNN; k0 += 8) {
        float aval = 0.f;
        float4 bv = *(const float4*)(brow + k0);
        if (t < 128) {
            const int k = k0 + ak;
            float pre = b4s[k];
            #pragma unroll
            for (int o = 0; o < 10; ++o) pre += w4s[k * 10 + o] * v4r[o];
            aval = arow[k0 + ak] + alpha * fmaxf(pre, 0.f);
        }
        __syncthreads();
        if (t < 128) As[ak * 20 + am] = aval;
        Bs[(bk4 + 0) * 136 + bn_] = bv.x; Bs[(bk4 + 1) * 136 + bn_] = bv.y;
        Bs[(bk4 + 2) * 136 + bn_] = bv.z; Bs[(bk4 + 3) * 136 + bn_] = bv.w;
        __syncthreads();
        #pragma unroll
        for (int kk = 0; kk < 8; ++kk) {
            float2 av  = *(const float2*)&As[kk * 20 + ty * 2];
            float4 bv4 = *(const float4*)&Bs[kk * 136 + tx * 4];
            #pragma unroll
            for (int j = 0; j < 4; ++j) {
                float b = (&bv4.x)[j];
                acc[0][j] += av.x * b;
                acc[1][j] += av.y * b;
            }
        }
    }

    if (!last) {
        #pragma unroll
        for (int i = 0; i < 2; ++i) {
            const int m = ty * 2 + i;
            #pragma unroll
            for (int j = 0; j < 4; ++j) {
                const int n = tx * 4 + j;
                Ct[m * 133 + n] = fmaxf(acc[i][j] + bds[n], 0.f);
            }
        }
        __syncthreads();
        if (t < 160) {
            const int rr = t / 10, o = t % 10;
            float s = ab1s[o];
            #pragma unroll 8
            for (int k = 0; k < 128; ++k) s += Ct[rr * 133 + k] * aw1t[k * 10 + o];
            v4s[rr * 12 + o] = fmaxf(s, 0.f);   // reuse v4s as v1 storage
        }
        __syncthreads();
        if (t < 16) {
            float vv[10];
            #pragma unroll
            for (int o = 0; o < 10; ++o) vv[o] = v4s[t * 12 + o];
            #pragma unroll
            for (int p = 0; p < 5; ++p) {
                float s = ab2s[p];
                #pragma unroll
                for (int o = 0; o < 10; ++o) s += aw2s[p * 10 + o] * vv[o];
                V2out[(size_t)(m0 + t) * 8 + p] = fmaxf(s, 0.f);
            }
        }
    } else {
        #pragma unroll
        for (int i = 0; i < 2; ++i) {
            const int m = ty * 2 + i;
            float4 ov = make_float4(fmaxf(acc[i][0] + bds[tx * 4 + 0], 0.f),
                                    fmaxf(acc[i][1] + bds[tx * 4 + 1], 0.f),
                                    fmaxf(acc[i][2] + bds[tx * 4 + 2], 0.f),
                                    fmaxf(acc[i][3] + bds[tx * 4 + 3], 0.f));
            Ct[m * 133 + tx * 4 + 0] = ov.x; Ct[m * 133 + tx * 4 + 1] = ov.y;
            Ct[m * 133 + tx * 4 + 2] = ov.z; Ct[m * 133 + tx * 4 + 3] = ov.w;
            *(float4*)(outV + (size_t)(m0 + m) * CNN + tx * 4) = ov;
        }
        __syncthreads();
        // H_R rows: HR[16x200] = Ct[16x128] @ wdt[128x200]
        if (t < CIN) {
            float hr[16];
            #pragma unroll
            for (int i = 0; i < 16; ++i) hr[i] = 0.f;
            for (int k = 0; k < 128; ++k) {
                const float wk = wdt[(size_t)k * CIN + t];
                #pragma unroll
                for (int i = 0; i < 16; ++i) hr[i] += Ct[i * 133 + k] * wk;
            }
            #pragma unroll
            for (int i = 0; i < 16; ++i)
                outHR[(size_t)(m0 + i) * CIN + t] = hr[i];
        }
    }
}

// --------------------------------------------------------------- launcher
extern "C" void kernel_launch(void* const* d_in, const int* in_sizes, int n_in,
                              void* d_out, int out_size, void* d_ws, size_t ws_size,
                              hipStream_t stream)
{
    (void)in_sizes; (void)n_in; (void)out_size; (void)ws_size;
    const float* H     = (const float*)d_in[0];
    const float* alpha = (const float*)d_in[1];
    const float* gamma = (const float*)d_in[2];
    const float* beta  = (const float*)d_in[3];
    const float* w1    = (const float*)d_in[4];
    const float* b1    = (const float*)d_in[5];
    const float* wdt   = (const float*)d_in[6];
    const float* bdt   = (const float*)d_in[7];
    const float* wdtd  = (const float*)d_in[8];
    const float* bdtd  = (const float*)d_in[9];
    const float* aw1   = (const float*)d_in[10];
    const float* ab1   = (const float*)d_in[11];
    const float* aw2   = (const float*)d_in[12];
    const float* ab2   = (const float*)d_in[13];
    const float* aw3   = (const float*)d_in[14];
    const float* ab3   = (const float*)d_in[15];
    const float* aw4   = (const float*)d_in[16];
    const float* ab4   = (const float*)d_in[17];

    float* ws   = (float*)d_ws;
    float* DTH  = ws + OFF_DTH;
    float* V2a  = ws + OFF_V2A;
    float* V2b  = ws + OFF_V2B;

    float* outV  = (float*)d_out;
    float* outHR = outV + (size_t)NR * CNN;

    bn1_k<<<64, 256, 0, stream>>>(H, ws);
    gemm_bn_k<<<512, 256, 0, stream>>>(H, w1, b1, wdt, bdt, aw1, ab1, aw2, ab2,
                                       gamma, beta, ws, DTH, V2a);
    fused_iter_k<<<512, 256, 0, stream>>>(V2a, V2b, DTH, alpha, wdtd, bdtd,
                                          aw4, ab4, aw1, ab1, aw2, ab2, aw3, ab3,
                                          wdt, nullptr, nullptr);
    fused_iter_k<<<512, 256, 0, stream>>>(V2b, V2a, DTH, alpha, wdtd, bdtd,
                                          aw4, ab4, aw1, ab1, aw2, ab2, aw3, ab3,
                                          wdt, nullptr, nullptr);
    fused_iter_k<<<512, 256, 0, stream>>>(V2a, V2b, DTH, alpha, wdtd, bdtd,
                                          aw4, ab4, aw1, ab1, aw2, ab2, aw3, ab3,
                                          wdt, outV, outHR);
}

// Round 7
// 139.833 us; speedup vs baseline: 5.0140x; 1.4910x over previous
//
#include <hip/hip_runtime.h>
#include <hip/hip_fp16.h>

#define NR   8192
#define CIN  200
#define CNN  128
#define BN_EPS 1e-5f
#define CHUNK 512
#define LA_STRIDE 24          // halfs per layoutA row (48 B)
#define LB_STRIDE (CHUNK + 4) // halfs per layoutB row (padded vs bank conflicts)

typedef _Float16 f16x4 __attribute__((ext_vector_type(4)));
typedef float    f32x4 __attribute__((ext_vector_type(4)));

// ws float offsets
#define OFF_BNPART 0                          // 64 blocks * 400
#define OFF_DTH    (OFF_BNPART + 64 * 400)
#define OFF_V2A    (OFF_DTH + NR * CNN)       // fp16 NR*8 = NR*4 floats
#define OFF_V2B    (OFF_V2A + NR * 4)

// ---------------- BN pass 1: row-block partial sums ------------------------
__global__ __launch_bounds__(256) void bn1_k(
    const float* __restrict__ H, float* __restrict__ ws)
{
    const int t = threadIdx.x;
    if (t >= CIN) return;
    const float* p = H + (size_t)blockIdx.x * 128 * CIN + t;
    float s = 0.f, q = 0.f;
    #pragma unroll 8
    for (int r = 0; r < 128; ++r) { float v = p[(size_t)r * CIN]; s += v; q += v * v; }
    ws[OFF_BNPART + blockIdx.x * 400 + t]       = s;
    ws[OFF_BNPART + blockIdx.x * 400 + 200 + t] = q;
}

// ---------------- BN finalize + dual GEMM + l12 epilogue -------------------
__global__ __launch_bounds__(256) void gemm_bn_k(
    const float* __restrict__ H, const float* __restrict__ w1,
    const float* __restrict__ b1, const float* __restrict__ wdt,
    const float* __restrict__ bdt,
    const float* __restrict__ aw1, const float* __restrict__ ab1,
    const float* __restrict__ aw2, const float* __restrict__ ab2,
    const float* __restrict__ gamma, const float* __restrict__ beta,
    float* __restrict__ ws, float* __restrict__ DTH, _Float16* __restrict__ V2)
{
    __shared__ float smem[8192];
    float* scs  = smem;          // 256
    float* shs  = smem + 256;    // 256
    float* bias = smem + 512;    // 128
    float* aw1s = smem + 768;    // 1280
    float* aw2s = smem + 2048;   // 64
    float* ab1s = smem + 2112;   // 16
    float* ab2s = smem + 2128;   // 16
    float* As   = smem + 2144;   // [8][36]
    float* Bs   = smem + 2432;   // [8][136]
    float* Ct   = smem + 3520;   // [32][133]
    float* v1s  = smem + 7776;   // [32][12]

    const int t   = threadIdx.x;
    const int bid = blockIdx.x;
    const bool isV = (bid < 256);
    const int  m0  = (bid & 255) * 32;
    const float* bnpart = ws + OFF_BNPART;

    if (t < CIN) {
        float s = 0.f, q = 0.f;
        const float* p = bnpart + t;
        #pragma unroll 8
        for (int b = 0; b < 64; ++b) { s += p[b * 400]; q += p[b * 400 + 200]; }
        float mu  = s * (1.f / NR);
        float var = q * (1.f / NR) - mu * mu;
        float sc  = rsqrtf(var + BN_EPS) * gamma[t];
        scs[t] = sc; shs[t] = beta[t] - mu * sc;
    }
    if (t < CNN) bias[t] = isV ? b1[t] : bdt[t];
    if (isV) {
        for (int i = t; i < 1280; i += 256) aw1s[i] = aw1[i];
        if (t < 50) aw2s[t] = aw2[t];
        if (t < 10) ab1s[t] = ab1[t];
        if (t < 5)  ab2s[t] = ab2[t];
    }
    const int am = t >> 3, ak = t & 7;
    const int bn_ = t >> 1, bk4 = (t & 1) * 4;
    const float* brow = (isV ? w1 : wdt) + (size_t)bn_ * CIN + bk4;
    const float* arow = H + (size_t)(m0 + am) * CIN + ak;
    const int tx = t & 31, ty = t >> 5;
    float acc[4][4] = {};
    __syncthreads();

    for (int k0 = 0; k0 < CIN; k0 += 8) {
        const int k = k0 + ak;
        float  aval = arow[k0] * scs[k] + shs[k];
        float4 bv   = *(const float4*)(brow + k0);
        __syncthreads();
        As[ak * 36 + am] = aval;
        Bs[(bk4 + 0) * 136 + bn_] = bv.x; Bs[(bk4 + 1) * 136 + bn_] = bv.y;
        Bs[(bk4 + 2) * 136 + bn_] = bv.z; Bs[(bk4 + 3) * 136 + bn_] = bv.w;
        __syncthreads();
        #pragma unroll
        for (int kk = 0; kk < 8; ++kk) {
            float4 av  = *(const float4*)&As[kk * 36 + ty * 4];
            float4 bv4 = *(const float4*)&Bs[kk * 136 + tx * 4];
            float a[4] = {av.x, av.y, av.z, av.w};
            float b[4] = {bv4.x, bv4.y, bv4.z, bv4.w};
            #pragma unroll
            for (int i = 0; i < 4; ++i)
                #pragma unroll
                for (int j = 0; j < 4; ++j)
                    acc[i][j] += a[i] * b[j];
        }
    }

    if (isV) {
        #pragma unroll
        for (int i = 0; i < 4; ++i) {
            const int m = ty * 4 + i;
            #pragma unroll
            for (int j = 0; j < 4; ++j) {
                const int n = tx * 4 + j;
                Ct[m * 133 + n] = fmaxf(acc[i][j] + bias[n], 0.f);
            }
        }
        __syncthreads();
        for (int o = ty; o < 10; o += 8) {
            const int row = tx;
            float s = ab1s[o];
            const float* wr = &aw1s[o * 128];
            #pragma unroll 8
            for (int k = 0; k < 128; ++k) s += Ct[row * 133 + k] * wr[k];
            v1s[row * 12 + o] = fmaxf(s, 0.f);
        }
        __syncthreads();
        if (t < 32) {
            float vv[10];
            #pragma unroll
            for (int o = 0; o < 10; ++o) vv[o] = v1s[t * 12 + o];
            _Float16 h8[8];
            #pragma unroll
            for (int p = 0; p < 5; ++p) {
                float s = ab2s[p];
                #pragma unroll
                for (int o = 0; o < 10; ++o) s += aw2s[p * 10 + o] * vv[o];
                h8[p] = (_Float16)fmaxf(s, 0.f);
            }
            h8[5] = (_Float16)0.f; h8[6] = (_Float16)0.f; h8[7] = (_Float16)0.f;
            *(float4*)(V2 + (size_t)(m0 + t) * 8) = *(float4*)h8;
        }
    } else {
        #pragma unroll
        for (int i = 0; i < 4; ++i) {
            const int m = m0 + ty * 4 + i;
            float4 ov = make_float4(acc[i][0] + bias[tx * 4 + 0],
                                    acc[i][1] + bias[tx * 4 + 1],
                                    acc[i][2] + bias[tx * 4 + 2],
                                    acc[i][3] + bias[tx * 4 + 3]);
            *(float4*)(DTH + (size_t)m * CNN + tx * 4) = ov;
        }
    }
}

// ---------------- fused iteration: MFMA flash attn + L3 + L4 + GEMM --------
// 512 blocks x 16 rows. Swapped QK^T (S^T = K*Q^T) so P lands in the PV
// A-fragment with no cross-lane moves; V padded with a 1.0 column so PV
// emits numerators AND denominator in one MFMA.
__global__ __launch_bounds__(256, 2) void fused_iter_k(
    const _Float16* __restrict__ V2in, _Float16* __restrict__ V2out,
    const float* __restrict__ DTH,  const float* __restrict__ alpha_p,
    const float* __restrict__ wdtd, const float* __restrict__ bdtd,
    const float* __restrict__ aw4,  const float* __restrict__ ab4,
    const float* __restrict__ aw1,  const float* __restrict__ ab1,
    const float* __restrict__ aw2,  const float* __restrict__ ab2,
    const float* __restrict__ aw3,  const float* __restrict__ ab3,
    const float* __restrict__ wdt,
    float* __restrict__ outV, float* __restrict__ outHR)
{
    __shared__ _Float16 layoutA[CHUNK * LA_STRIDE];   // 24 KB; GEMM reuses as f32
    __shared__ _Float16 layoutB[16 * LB_STRIDE];      // 16.5 KB  [outc][key]
    __shared__ _Float16 Qs[16 * 16];                  // 512 B
    __shared__ float w4s[1280], aw1t[1280];
    __shared__ float b4s[128], bds[128];
    __shared__ float w3s[52], b3s[12], ab1s[12], aw2s[52], ab2s[8];
    __shared__ float v4s[16 * 12];
    __shared__ float wred[4 * 16 * 6];

    const int t    = threadIdx.x;
    const int bid  = blockIdx.x;
    const int m0   = bid * 16;
    const bool last = (outV != nullptr);
    const int lane = t & 63, wv = t >> 6;
    const int g = lane >> 4, lq = lane & 15;

    // ---- stage weights + one-time zero/const regions ----
    for (int i = t; i < 1280; i += 256) {
        w4s[i] = aw4[i];
        const int o = i >> 7, k = i & 127;
        aw1t[k * 10 + o] = aw1[i];
    }
    if (t < 128) { b4s[t] = ab4[t]; bds[t] = bdtd[t]; }
    if (t < 50)  { w3s[t] = aw3[t]; aw2s[t] = aw2[t]; }
    if (t < 10)  { b3s[t] = ab3[t]; ab1s[t] = ab1[t]; }
    if (t < 5)   ab2s[t] = ab2[t];
    // layoutA cols 8..23 = 0 (K-dim zero padding for the K=16 MFMA)
    {
        const float4 z4 = make_float4(0.f, 0.f, 0.f, 0.f);
        for (int i = t; i < CHUNK; i += 256) {
            *(float4*)&layoutA[i * LA_STRIDE + 8]  = z4;
            *(float4*)&layoutA[i * LA_STRIDE + 16] = z4;
        }
    }
    // layoutB row5 = 1.0 (denominator column), rows 6..15 = 0
    for (int i = t; i < LB_STRIDE; i += 256) layoutB[5 * LB_STRIDE + i] = (_Float16)1.f;
    for (int i = t; i < 10 * LB_STRIDE; i += 256) layoutB[6 * LB_STRIDE + i] = (_Float16)0.f;
    // Q tile (16 rows x 16 halfs, cols 8..15 zero)
    if (t < 16) {
        float4 qv = *(const float4*)(V2in + (size_t)(m0 + t) * 8);
        *(float4*)&Qs[t * 16]     = qv;
        *(float4*)&Qs[t * 16 + 8] = make_float4(0.f, 0.f, 0.f, 0.f);
    }
    __syncthreads();

    // Q fragment (B-operand), constant over the whole key loop
    const f16x4 qfrag = *(const f16x4*)&Qs[lq * 16 + g * 4];

    f32x4 accA = {0.f, 0.f, 0.f, 0.f};
    f32x4 accB = {0.f, 0.f, 0.f, 0.f};

    for (int ch = 0; ch < NR / CHUNK; ++ch) {
        __syncthreads();
        // stage chunk: 2 keys per thread (16B coalesced reads)
        #pragma unroll
        for (int rr = 0; rr < 2; ++rr) {
            const int k = t + rr * 256;
            float4 src = *(const float4*)(V2in + ((size_t)ch * CHUNK + k) * 8);
            uint4 u = *(uint4*)&src;
            u.z = (u.z & 0xFFFFu) | (0x3C00u << 16);      // col5 := fp16 1.0
            *(float4*)&layoutA[k * LA_STRIDE] = *(float4*)&u;
            _Float16 h[8]; *(float4*)h = src;
            layoutB[0 * LB_STRIDE + k] = h[0];
            layoutB[1 * LB_STRIDE + k] = h[1];
            layoutB[2 * LB_STRIDE + k] = h[2];
            layoutB[3 * LB_STRIDE + k] = h[3];
            layoutB[4 * LB_STRIDE + k] = h[4];
        }
        __syncthreads();
        // 8 tiles of 16 keys per wave
        const int keybase = wv * 128;
        #pragma unroll 4
        for (int tl = 0; tl < 8; ++tl) {
            const int kb = keybase + tl * 16;
            f16x4 kfrag = *(const f16x4*)&layoutA[(kb + lq) * LA_STRIDE + g * 4];
            f32x4 st = __builtin_amdgcn_mfma_f32_16x16x16f16(
                kfrag, qfrag, (f32x4){0.f, 0.f, 0.f, 0.f}, 0, 0, 0);
            f16x4 pfrag;
            pfrag[0] = (_Float16)__expf(st[0]);
            pfrag[1] = (_Float16)__expf(st[1]);
            pfrag[2] = (_Float16)__expf(st[2]);
            pfrag[3] = (_Float16)__expf(st[3]);
            f16x4 vfrag = *(const f16x4*)&layoutB[lq * LB_STRIDE + kb + g * 4];
            if (tl & 1) accB = __builtin_amdgcn_mfma_f32_16x16x16f16(pfrag, vfrag, accB, 0, 0, 0);
            else        accA = __builtin_amdgcn_mfma_f32_16x16x16f16(pfrag, vfrag, accA, 0, 0, 0);
        }
    }
    accA[0] += accB[0]; accA[1] += accB[1]; accA[2] += accB[2]; accA[3] += accB[3];

    // cross-wave reduce: lane holds OUT[q=g*4+reg][outc=lq] partial
    __syncthreads();
    if (lq < 6) {
        #pragma unroll
        for (int i = 0; i < 4; ++i)
            wred[(wv * 16 + g * 4 + i) * 6 + lq] = accA[i];
    }
    __syncthreads();
    if (t < 16) {
        float n[6] = {0.f, 0.f, 0.f, 0.f, 0.f, 0.f};
        #pragma unroll
        for (int w = 0; w < 4; ++w)
            #pragma unroll
            for (int c = 0; c < 6; ++c) n[c] += wred[(w * 16 + t) * 6 + c];
        const float inv = 1.f / n[5];
        float av[5] = {n[0] * inv, n[1] * inv, n[2] * inv, n[3] * inv, n[4] * inv};
        #pragma unroll
        for (int o = 0; o < 10; ++o) {
            float s = b3s[o];
            #pragma unroll
            for (int c = 0; c < 5; ++c) s += w3s[o * 5 + c] * av[c];
            v4s[t * 12 + o] = fmaxf(s, 0.f);
        }
    }
    __syncthreads();

    // ---- GEMM: A[16x128] (L4 head) @ wdtd^T -> C[16x128]  (reuses layoutA) --
    float* As = (float*)layoutA;          // [8][20]
    float* Bs = (float*)layoutA + 160;    // [8][136]
    float* Ct = (float*)layoutA + 1248;   // [16][133]
    const float alpha = alpha_p[0];
    const int am = t >> 3, ak = t & 7;
    float v4r[10];
    if (t < 128) {
        #pragma unroll
        for (int o = 0; o < 10; ++o) v4r[o] = v4s[am * 12 + o];
    }
    const int bn_ = t >> 1, bk4 = (t & 1) * 4;
    const float* brow = wdtd + (size_t)bn_ * CNN + bk4;
    const float* arow = DTH + (size_t)(m0 + am) * CNN;
    const int tx = t & 31, ty = t >> 5;
    float acc[2][4] = {};

    for (int k0 = 0; k0 < CNN; k0 += 8) {
        float aval = 0.f;
        float4 bv = *(const float4*)(brow + k0);
        if (t < 128) {
            const int k = k0 + ak;
            float pre = b4s[k];
            #pragma unroll
            for (int o = 0; o < 10; ++o) pre += w4s[k * 10 + o] * v4r[o];
            aval = arow[k0 + ak] + alpha * fmaxf(pre, 0.f);
        }
        __syncthreads();
        if (t < 128) As[ak * 20 + am] = aval;
        Bs[(bk4 + 0) * 136 + bn_] = bv.x; Bs[(bk4 + 1) * 136 + bn_] = bv.y;
        Bs[(bk4 + 2) * 136 + bn_] = bv.z; Bs[(bk4 + 3) * 136 + bn_] = bv.w;
        __syncthreads();
        #pragma unroll
        for (int kk = 0; kk < 8; ++kk) {
            float2 av  = *(const float2*)&As[kk * 20 + ty * 2];
            float4 bv4 = *(const float4*)&Bs[kk * 136 + tx * 4];
            #pragma unroll
            for (int j = 0; j < 4; ++j) {
                float b = (&bv4.x)[j];
                acc[0][j] += av.x * b;
                acc[1][j] += av.y * b;
            }
        }
    }

    if (!last) {
        #pragma unroll
        for (int i = 0; i < 2; ++i) {
            const int m = ty * 2 + i;
            #pragma unroll
            for (int j = 0; j < 4; ++j) {
                const int n = tx * 4 + j;
                Ct[m * 133 + n] = fmaxf(acc[i][j] + bds[n], 0.f);
            }
        }
        __syncthreads();
        if (t < 160) {
            const int rr = t / 10, o = t % 10;
            float s = ab1s[o];
            #pragma unroll 8
            for (int k = 0; k < 128; ++k) s += Ct[rr * 133 + k] * aw1t[k * 10 + o];
            v4s[rr * 12 + o] = fmaxf(s, 0.f);   // reuse v4s as v1 storage
        }
        __syncthreads();
        if (t < 16) {
            float vv[10];
            #pragma unroll
            for (int o = 0; o < 10; ++o) vv[o] = v4s[t * 12 + o];
            _Float16 h8[8];
            #pragma unroll
            for (int p = 0; p < 5; ++p) {
                float s = ab2s[p];
                #pragma unroll
                for (int o = 0; o < 10; ++o) s += aw2s[p * 10 + o] * vv[o];
                h8[p] = (_Float16)fmaxf(s, 0.f);
            }
            h8[5] = (_Float16)0.f; h8[6] = (_Float16)0.f; h8[7] = (_Float16)0.f;
            *(float4*)(V2out + (size_t)(m0 + t) * 8) = *(float4*)h8;
        }
    } else {
        #pragma unroll
        for (int i = 0; i < 2; ++i) {
            const int m = ty * 2 + i;
            float4 ov = make_float4(fmaxf(acc[i][0] + bds[tx * 4 + 0], 0.f),
                                    fmaxf(acc[i][1] + bds[tx * 4 + 1], 0.f),
                                    fmaxf(acc[i][2] + bds[tx * 4 + 2], 0.f),
                                    fmaxf(acc[i][3] + bds[tx * 4 + 3], 0.f));
            Ct[m * 133 + tx * 4 + 0] = ov.x; Ct[m * 133 + tx * 4 + 1] = ov.y;
            Ct[m * 133 + tx * 4 + 2] = ov.z; Ct[m * 133 + tx * 4 + 3] = ov.w;
            *(float4*)(outV + (size_t)(m0 + m) * CNN + tx * 4) = ov;
        }
        __syncthreads();
        if (t < CIN) {
            float hr[16];
            #pragma unroll
            for (int i = 0; i < 16; ++i) hr[i] = 0.f;
            for (int k = 0; k < 128; ++k) {
                const float wk = wdt[(size_t)k * CIN + t];
                #pragma unroll
                for (int i = 0; i < 16; ++i) hr[i] += Ct[i * 133 + k] * wk;
            }
            #pragma unroll
            for (int i = 0; i < 16; ++i)
                outHR[(size_t)(m0 + i) * CIN + t] = hr[i];
        }
    }
}

// --------------------------------------------------------------- launcher
extern "C" void kernel_launch(void* const* d_in, const int* in_sizes, int n_in,
                              void* d_out, int out_size, void* d_ws, size_t ws_size,
                              hipStream_t stream)
{
    (void)in_sizes; (void)n_in; (void)out_size; (void)ws_size;
    const float* H     = (const float*)d_in[0];
    const float* alpha = (const float*)d_in[1];
    const float* gamma = (const float*)d_in[2];
    const float* beta  = (const float*)d_in[3];
    const float* w1    = (const float*)d_in[4];
    const float* b1    = (const float*)d_in[5];
    const float* wdt   = (const float*)d_in[6];
    const float* bdt   = (const float*)d_in[7];
    const float* wdtd  = (const float*)d_in[8];
    const float* bdtd  = (const float*)d_in[9];
    const float* aw1   = (const float*)d_in[10];
    const float* ab1   = (const float*)d_in[11];
    const float* aw2   = (const float*)d_in[12];
    const float* ab2   = (const float*)d_in[13];
    const float* aw3   = (const float*)d_in[14];
    const float* ab3   = (const float*)d_in[15];
    const float* aw4   = (const float*)d_in[16];
    const float* ab4   = (const float*)d_in[17];

    float* ws   = (float*)d_ws;
    float* DTH  = ws + OFF_DTH;
    _Float16* V2a = (_Float16*)(ws + OFF_V2A);
    _Float16* V2b = (_Float16*)(ws + OFF_V2B);

    float* outV  = (float*)d_out;
    float* outHR = outV + (size_t)NR * CNN;

    bn1_k<<<64, 256, 0, stream>>>(H, ws);
    gemm_bn_k<<<512, 256, 0, stream>>>(H, w1, b1, wdt, bdt, aw1, ab1, aw2, ab2,
                                       gamma, beta, ws, DTH, V2a);
    fused_iter_k<<<512, 256, 0, stream>>>(V2a, V2b, DTH, alpha, wdtd, bdtd,
                                          aw4, ab4, aw1, ab1, aw2, ab2, aw3, ab3,
                                          wdt, nullptr, nullptr);
    fused_iter_k<<<512, 256, 0, stream>>>(V2b, V2a, DTH, alpha, wdtd, bdtd,
                                          aw4, ab4, aw1, ab1, aw2, ab2, aw3, ab3,
                                          wdt, nullptr, nullptr);
    fused_iter_k<<<512, 256, 0, stream>>>(V2a, V2b, DTH, alpha, wdtd, bdtd,
                                          aw4, ab4, aw1, ab1, aw2, ab2, aw3, ab3,
                                          wdt, outV, outHR);
}

// Round 9
// 136.539 us; speedup vs baseline: 5.1349x; 1.0241x over previous
//
#include <hip/hip_runtime.h>
#include <hip/hip_fp16.h>

#define NR   8192
#define CIN  200
#define CNN  128
#define BN_EPS 1e-5f
#define CHUNK 512
#define LA_STRIDE 24          // halfs per layoutA row (48 B)
#define LBS (CHUNK + 4)       // halfs per layoutB row

typedef _Float16 f16x4 __attribute__((ext_vector_type(4)));
typedef float    f32x4 __attribute__((ext_vector_type(4)));

// ws float offsets
#define OFF_BNPART 0                          // 64 blocks * 400
#define OFF_DTH    (OFF_BNPART + 64 * 400)
#define OFF_V2A    (OFF_DTH + NR * CNN)       // fp16 NR*8 = NR*4 floats
#define OFF_V2B    (OFF_V2A + NR * 4)

// ---------------- BN pass 1: row-block partial sums ------------------------
__global__ __launch_bounds__(256) void bn1_k(
    const float* __restrict__ H, float* __restrict__ ws)
{
    const int t = threadIdx.x;
    if (t >= CIN) return;
    const float* p = H + (size_t)blockIdx.x * 128 * CIN + t;
    float s = 0.f, q = 0.f;
    #pragma unroll 8
    for (int r = 0; r < 128; ++r) { float v = p[(size_t)r * CIN]; s += v; q += v * v; }
    ws[OFF_BNPART + blockIdx.x * 400 + t]       = s;
    ws[OFF_BNPART + blockIdx.x * 400 + 200 + t] = q;
}

// ---------------- BN finalize + dual GEMM + l12 epilogue -------------------
__global__ __launch_bounds__(256) void gemm_bn_k(
    const float* __restrict__ H, const float* __restrict__ w1,
    const float* __restrict__ b1, const float* __restrict__ wdt,
    const float* __restrict__ bdt,
    const float* __restrict__ aw1, const float* __restrict__ ab1,
    const float* __restrict__ aw2, const float* __restrict__ ab2,
    const float* __restrict__ gamma, const float* __restrict__ beta,
    float* __restrict__ ws, float* __restrict__ DTH, _Float16* __restrict__ V2)
{
    __shared__ float smem[8192];
    float* scs  = smem;          // 256
    float* shs  = smem + 256;    // 256
    float* bias = smem + 512;    // 128
    float* aw1s = smem + 768;    // 1280
    float* aw2s = smem + 2048;   // 64
    float* ab1s = smem + 2112;   // 16
    float* ab2s = smem + 2128;   // 16
    float* As   = smem + 2144;   // [8][36]
    float* Bs   = smem + 2432;   // [8][136]
    float* Ct   = smem + 3520;   // [32][133]
    float* v1s  = smem + 7776;   // [32][12]

    const int t   = threadIdx.x;
    const int bid = blockIdx.x;
    const bool isV = (bid < 256);
    const int  m0  = (bid & 255) * 32;
    const float* bnpart = ws + OFF_BNPART;

    if (t < CIN) {
        float s = 0.f, q = 0.f;
        const float* p = bnpart + t;
        #pragma unroll 8
        for (int b = 0; b < 64; ++b) { s += p[b * 400]; q += p[b * 400 + 200]; }
        float mu  = s * (1.f / NR);
        float var = q * (1.f / NR) - mu * mu;
        float sc  = rsqrtf(var + BN_EPS) * gamma[t];
        scs[t] = sc; shs[t] = beta[t] - mu * sc;
    }
    if (t < CNN) bias[t] = isV ? b1[t] : bdt[t];
    if (isV) {
        for (int i = t; i < 1280; i += 256) aw1s[i] = aw1[i];
        if (t < 50) aw2s[t] = aw2[t];
        if (t < 10) ab1s[t] = ab1[t];
        if (t < 5)  ab2s[t] = ab2[t];
    }
    const int am = t >> 3, ak = t & 7;
    const int bn_ = t >> 1, bk4 = (t & 1) * 4;
    const float* brow = (isV ? w1 : wdt) + (size_t)bn_ * CIN + bk4;
    const float* arow = H + (size_t)(m0 + am) * CIN + ak;
    const int tx = t & 31, ty = t >> 5;
    float acc[4][4] = {};
    __syncthreads();

    for (int k0 = 0; k0 < CIN; k0 += 8) {
        const int k = k0 + ak;
        float  aval = arow[k0] * scs[k] + shs[k];
        float4 bv   = *(const float4*)(brow + k0);
        __syncthreads();
        As[ak * 36 + am] = aval;
        Bs[(bk4 + 0) * 136 + bn_] = bv.x; Bs[(bk4 + 1) * 136 + bn_] = bv.y;
        Bs[(bk4 + 2) * 136 + bn_] = bv.z; Bs[(bk4 + 3) * 136 + bn_] = bv.w;
        __syncthreads();
        #pragma unroll
        for (int kk = 0; kk < 8; ++kk) {
            float4 av  = *(const float4*)&As[kk * 36 + ty * 4];
            float4 bv4 = *(const float4*)&Bs[kk * 136 + tx * 4];
            float a[4] = {av.x, av.y, av.z, av.w};
            float b[4] = {bv4.x, bv4.y, bv4.z, bv4.w};
            #pragma unroll
            for (int i = 0; i < 4; ++i)
                #pragma unroll
                for (int j = 0; j < 4; ++j)
                    acc[i][j] += a[i] * b[j];
        }
    }

    if (isV) {
        #pragma unroll
        for (int i = 0; i < 4; ++i) {
            const int m = ty * 4 + i;
            #pragma unroll
            for (int j = 0; j < 4; ++j) {
                const int n = tx * 4 + j;
                Ct[m * 133 + n] = fmaxf(acc[i][j] + bias[n], 0.f);
            }
        }
        __syncthreads();
        for (int o = ty; o < 10; o += 8) {
            const int row = tx;
            float s = ab1s[o];
            const float* wr = &aw1s[o * 128];
            #pragma unroll 8
            for (int k = 0; k < 128; ++k) s += Ct[row * 133 + k] * wr[k];
            v1s[row * 12 + o] = fmaxf(s, 0.f);
        }
        __syncthreads();
        if (t < 32) {
            float vv[10];
            #pragma unroll
            for (int o = 0; o < 10; ++o) vv[o] = v1s[t * 12 + o];
            _Float16 h8[8];
            #pragma unroll
            for (int p = 0; p < 5; ++p) {
                float s = ab2s[p];
                #pragma unroll
                for (int o = 0; o < 10; ++o) s += aw2s[p * 10 + o] * vv[o];
                h8[p] = (_Float16)fmaxf(s, 0.f);
            }
            h8[5] = (_Float16)0.f; h8[6] = (_Float16)0.f; h8[7] = (_Float16)0.f;
            *(float4*)(V2 + (size_t)(m0 + t) * 8) = *(float4*)h8;
        }
    } else {
        #pragma unroll
        for (int i = 0; i < 4; ++i) {
            const int m = m0 + ty * 4 + i;
            float4 ov = make_float4(acc[i][0] + bias[tx * 4 + 0],
                                    acc[i][1] + bias[tx * 4 + 1],
                                    acc[i][2] + bias[tx * 4 + 2],
                                    acc[i][3] + bias[tx * 4 + 3]);
            *(float4*)(DTH + (size_t)m * CNN + tx * 4) = ov;
        }
    }
}

// ---------------- fused iteration: MFMA flash attn + L3 + L4 + GEMM --------
// 512 blocks x 512 threads (8 waves) x 16 rows. Swapped QK^T; V padded with
// a 1.0 column so PV emits numerators AND denominator in one MFMA.
__global__ __launch_bounds__(512, 4) void fused_iter_k(
    const _Float16* __restrict__ V2in, _Float16* __restrict__ V2out,
    const float* __restrict__ DTH,  const float* __restrict__ alpha_p,
    const float* __restrict__ wdtd, const float* __restrict__ bdtd,
    const float* __restrict__ aw4,  const float* __restrict__ ab4,
    const float* __restrict__ aw1,  const float* __restrict__ ab1,
    const float* __restrict__ aw2,  const float* __restrict__ ab2,
    const float* __restrict__ aw3,  const float* __restrict__ ab3,
    const float* __restrict__ wdt,
    float* __restrict__ outV, float* __restrict__ outHR)
{
    __shared__ _Float16 smemh[CHUNK * LA_STRIDE + 16 * LBS];  // 41 KB
    __shared__ _Float16 Qs[16 * 16];
    __shared__ float w4s[1280], aw1t[1280];
    __shared__ float b4s[128], bds[128];
    __shared__ float w3s[52], b3s[12], ab1s[12], aw2s[52], ab2s[8];
    __shared__ float v4s[16 * 12];
    __shared__ float wred[8 * 16 * 6];

    _Float16* layoutA = smemh;                 // [key][24]
    _Float16* layoutB = smemh + CHUNK * LA_STRIDE;  // [outc 0..15][key]

    const int t    = threadIdx.x;
    const int bid  = blockIdx.x;
    const int m0   = bid * 16;
    const bool last = (outV != nullptr);
    const int lane = t & 63, wv = t >> 6;      // wv 0..7
    const int g = lane >> 4, lq = lane & 15;

    // ---- stage weights + one-time zero/const regions ----
    for (int i = t; i < 1280; i += 512) {
        w4s[i] = aw4[i];
        const int o = i >> 7, k = i & 127;
        aw1t[k * 10 + o] = aw1[i];
    }
    if (t < 128) { b4s[t] = ab4[t]; bds[t] = bdtd[t]; }
    if (t < 50)  { w3s[t] = aw3[t]; aw2s[t] = aw2[t]; }
    if (t < 10)  { b3s[t] = ab3[t]; ab1s[t] = ab1[t]; }
    if (t < 5)   ab2s[t] = ab2[t];
    // layoutA cols 8..23 = 0 (K-dim padding), once
    {
        const float4 z4 = make_float4(0.f, 0.f, 0.f, 0.f);
        *(float4*)&layoutA[t * LA_STRIDE + 8]  = z4;
        *(float4*)&layoutA[t * LA_STRIDE + 16] = z4;
    }
    // layoutB row5 = 1.0 (denominator), rows 6..15 = 0, once
    for (int i = t; i < LBS; i += 512) layoutB[5 * LBS + i] = (_Float16)1.f;
    for (int i = t; i < 10 * LBS; i += 512) layoutB[6 * LBS + i] = (_Float16)0.f;
    // Q tile (16 rows x 16 halfs, cols 8..15 zero)
    if (t < 16) {
        float4 qv = *(const float4*)(V2in + (size_t)(m0 + t) * 8);
        *(float4*)&Qs[t * 16]     = qv;
        *(float4*)&Qs[t * 16 + 8] = make_float4(0.f, 0.f, 0.f, 0.f);
    }
    __syncthreads();

    const f16x4 qfrag = *(const f16x4*)&Qs[lq * 16 + g * 4];

    f32x4 accT[4] = {{0.f,0.f,0.f,0.f},{0.f,0.f,0.f,0.f},
                     {0.f,0.f,0.f,0.f},{0.f,0.f,0.f,0.f}};

    for (int ch = 0; ch < NR / CHUNK; ++ch) {
        __syncthreads();
        // stage chunk: 1 key per thread (16B coalesced read)
        {
            const int k = t;
            float4 src = *(const float4*)(V2in + ((size_t)ch * CHUNK + k) * 8);
            uint4 u = *(uint4*)&src;
            u.z = (u.z & 0xFFFFu) | (0x3C00u << 16);      // col5 := fp16 1.0
            *(float4*)&layoutA[k * LA_STRIDE] = *(float4*)&u;
            _Float16 h[8]; *(float4*)h = src;
            layoutB[0 * LBS + k] = h[0];
            layoutB[1 * LBS + k] = h[1];
            layoutB[2 * LBS + k] = h[2];
            layoutB[3 * LBS + k] = h[3];
            layoutB[4 * LBS + k] = h[4];
        }
        __syncthreads();
        // 4 tiles of 16 keys per wave, 4 independent acc chains
        const int keybase = wv * 64;
        #pragma unroll
        for (int tl = 0; tl < 4; ++tl) {
            const int kb = keybase + tl * 16;
            f16x4 kfrag = *(const f16x4*)&layoutA[(kb + lq) * LA_STRIDE + g * 4];
            f32x4 st = __builtin_amdgcn_mfma_f32_16x16x16f16(
                kfrag, qfrag, (f32x4){0.f, 0.f, 0.f, 0.f}, 0, 0, 0);
            auto p01 = __builtin_amdgcn_cvt_pkrtz(__expf(st[0]), __expf(st[1]));
            auto p23 = __builtin_amdgcn_cvt_pkrtz(__expf(st[2]), __expf(st[3]));
            f16x4 pfrag = {(_Float16)p01[0], (_Float16)p01[1],
                           (_Float16)p23[0], (_Float16)p23[1]};
            f16x4 vfrag = *(const f16x4*)&layoutB[lq * LBS + kb + g * 4];
            accT[tl] = __builtin_amdgcn_mfma_f32_16x16x16f16(pfrag, vfrag, accT[tl], 0, 0, 0);
        }
    }
    f32x4 accA = accT[0];
    accA[0] += accT[1][0] + accT[2][0] + accT[3][0];
    accA[1] += accT[1][1] + accT[2][1] + accT[3][1];
    accA[2] += accT[1][2] + accT[2][2] + accT[3][2];
    accA[3] += accT[1][3] + accT[2][3] + accT[3][3];

    // cross-wave reduce: lane holds OUT[q=g*4+i][outc=lq] partial
    __syncthreads();
    if (lq < 6) {
        #pragma unroll
        for (int i = 0; i < 4; ++i)
            wred[(wv * 16 + g * 4 + i) * 6 + lq] = accA[i];
    }
    __syncthreads();
    if (t < 16) {
        float n[6] = {0.f, 0.f, 0.f, 0.f, 0.f, 0.f};
        #pragma unroll
        for (int w = 0; w < 8; ++w)
            #pragma unroll
            for (int c = 0; c < 6; ++c) n[c] += wred[(w * 16 + t) * 6 + c];
        const float inv = 1.f / n[5];
        float av[5] = {n[0] * inv, n[1] * inv, n[2] * inv, n[3] * inv, n[4] * inv};
        #pragma unroll
        for (int o = 0; o < 10; ++o) {
            float s = b3s[o];
            #pragma unroll
            for (int c = 0; c < 5; ++c) s += w3s[o * 5 + c] * av[c];
            v4s[t * 12 + o] = fmaxf(s, 0.f);
        }
    }
    __syncthreads();

    // ---- GEMM: A[16x128] (L4 head) @ wdtd^T -> C[16x128]  (reuses smemh) ---
    float* As = (float*)smemh;          // [8][20]
    float* Bs = (float*)smemh + 160;    // [8][136]
    float* Ct = (float*)smemh + 1248;   // [16][133]
    const float alpha = alpha_p[0];
    const int am = t >> 3, ak = t & 7;            // t<128: A staging
    float v4r[10];
    if (t < 128) {
        #pragma unroll
        for (int o = 0; o < 10; ++o) v4r[o] = v4s[am * 12 + o];
    }
    const bool doB = (t < 256);
    const int bn_ = t >> 1, bk4 = (t & 1) * 4;    // t<256: B staging
    const float* brow = wdtd + (size_t)(doB ? bn_ : 0) * CNN + bk4;
    const float* arow = DTH + (size_t)(m0 + (am & 15)) * CNN;
    const int tx = t & 31, ty = t >> 5;           // ty 0..15 = m, n = tx*4
    float acc[4] = {};

    for (int k0 = 0; k0 < CNN; k0 += 8) {
        float aval = 0.f;
        float4 bv = make_float4(0.f, 0.f, 0.f, 0.f);
        if (doB) bv = *(const float4*)(brow + k0);
        if (t < 128) {
            const int k = k0 + ak;
            float pre = b4s[k];
            #pragma unroll
            for (int o = 0; o < 10; ++o) pre += w4s[k * 10 + o] * v4r[o];
            aval = arow[k0 + ak] + alpha * fmaxf(pre, 0.f);
        }
        __syncthreads();
        if (t < 128) As[ak * 20 + am] = aval;
        if (doB) {
            Bs[(bk4 + 0) * 136 + bn_] = bv.x; Bs[(bk4 + 1) * 136 + bn_] = bv.y;
            Bs[(bk4 + 2) * 136 + bn_] = bv.z; Bs[(bk4 + 3) * 136 + bn_] = bv.w;
        }
        __syncthreads();
        #pragma unroll
        for (int kk = 0; kk < 8; ++kk) {
            float a    = As[kk * 20 + ty];
            float4 bv4 = *(const float4*)&Bs[kk * 136 + tx * 4];
            acc[0] += a * bv4.x; acc[1] += a * bv4.y;
            acc[2] += a * bv4.z; acc[3] += a * bv4.w;
        }
    }

    if (!last) {
        #pragma unroll
        for (int j = 0; j < 4; ++j) {
            const int n = tx * 4 + j;
            Ct[ty * 133 + n] = fmaxf(acc[j] + bds[n], 0.f);
        }
        __syncthreads();
        if (t < 160) {
            const int rr = t / 10, o = t % 10;
            float s = ab1s[o];
            #pragma unroll 8
            for (int k = 0; k < 128; ++k) s += Ct[rr * 133 + k] * aw1t[k * 10 + o];
            v4s[rr * 12 + o] = fmaxf(s, 0.f);   // reuse v4s as v1 storage
        }
        __syncthreads();
        if (t < 16) {
            float vv[10];
            #pragma unroll
            for (int o = 0; o < 10; ++o) vv[o] = v4s[t * 12 + o];
            _Float16 h8[8];
            #pragma unroll
            for (int p = 0; p < 5; ++p) {
                float s = ab2s[p];
                #pragma unroll
                for (int o = 0; o < 10; ++o) s += aw2s[p * 10 + o] * vv[o];
                h8[p] = (_Float16)fmaxf(s, 0.f);
            }
            h8[5] = (_Float16)0.f; h8[6] = (_Float16)0.f; h8[7] = (_Float16)0.f;
            *(float4*)(V2out + (size_t)(m0 + t) * 8) = *(float4*)h8;
        }
    } else {
        float4 ov = make_float4(fmaxf(acc[0] + bds[tx * 4 + 0], 0.f),
                                fmaxf(acc[1] + bds[tx * 4 + 1], 0.f),
                                fmaxf(acc[2] + bds[tx * 4 + 2], 0.f),
                                fmaxf(acc[3] + bds[tx * 4 + 3], 0.f));
        Ct[ty * 133 + tx * 4 + 0] = ov.x; Ct[ty * 133 + tx * 4 + 1] = ov.y;
        Ct[ty * 133 + tx * 4 + 2] = ov.z; Ct[ty * 133 + tx * 4 + 3] = ov.w;
        *(float4*)(outV + (size_t)(m0 + ty) * CNN + tx * 4) = ov;
        __syncthreads();
        if (t < CIN) {
            float hr[16];
            #pragma unroll
            for (int i = 0; i < 16; ++i) hr[i] = 0.f;
            for (int k = 0; k < 128; ++k) {
                const float wk = wdt[(size_t)k * CIN + t];
                #pragma unroll
                for (int i = 0; i < 16; ++i) hr[i] += Ct[i * 133 + k] * wk;
            }
            #pragma unroll
            for (int i = 0; i < 16; ++i)
                outHR[(size_t)(m0 + i) * CIN + t] = hr[i];
        }
    }
}

// --------------------------------------------------------------- launcher
extern "C" void kernel_launch(void* const* d_in, const int* in_sizes, int n_in,
                              void* d_out, int out_size, void* d_ws, size_t ws_size,
                              hipStream_t stream)
{
    (void)in_sizes; (void)n_in; (void)out_size; (void)ws_size;
    const float* H     = (const float*)d_in[0];
    const float* alpha = (const float*)d_in[1];
    const float* gamma = (const float*)d_in[2];
    const float* beta  = (const float*)d_in[3];
    const float* w1    = (const float*)d_in[4];
    const float* b1    = (const float*)d_in[5];
    const float* wdt   = (const float*)d_in[6];
    const float* bdt   = (const float*)d_in[7];
    const float* wdtd  = (const float*)d_in[8];
    const float* bdtd  = (const float*)d_in[9];
    const float* aw1   = (const float*)d_in[10];
    const float* ab1   = (const float*)d_in[11];
    const float* aw2   = (const float*)d_in[12];
    const float* ab2   = (const float*)d_in[13];
    const float* aw3   = (const float*)d_in[14];
    const float* ab3   = (const float*)d_in[15];
    const float* aw4   = (const float*)d_in[16];
    const float* ab4   = (const float*)d_in[17];

    float* ws   = (float*)d_ws;
    float* DTH  = ws + OFF_DTH;
    _Float16* V2a = (_Float16*)(ws + OFF_V2A);
    _Float16* V2b = (_Float16*)(ws + OFF_V2B);

    float* outV  = (float*)d_out;
    float* outHR = outV + (size_t)NR * CNN;

    bn1_k<<<64, 256, 0, stream>>>(H, ws);
    gemm_bn_k<<<512, 256, 0, stream>>>(H, w1, b1, wdt, bdt, aw1, ab1, aw2, ab2,
                                       gamma, beta, ws, DTH, V2a);
    fused_iter_k<<<512, 512, 0, stream>>>(V2a, V2b, DTH, alpha, wdtd, bdtd,
                                          aw4, ab4, aw1, ab1, aw2, ab2, aw3, ab3,
                                          wdt, nullptr, nullptr);
    fused_iter_k<<<512, 512, 0, stream>>>(V2b, V2a, DTH, alpha, wdtd, bdtd,
                                          aw4, ab4, aw1, ab1, aw2, ab2, aw3, ab3,
                                          wdt, nullptr, nullptr);
    fused_iter_k<<<512, 512, 0, stream>>>(V2a, V2b, DTH, alpha, wdtd, bdtd,
                                          aw4, ab4, aw1, ab1, aw2, ab2, aw3, ab3,
                                          wdt, outV, outHR);
}